// Round 3
// baseline (3501.118 us; speedup 1.0000x reference)
//
#include <hip/hip_runtime.h>

typedef _Float16 f16;
typedef _Float16 f16x8 __attribute__((ext_vector_type(8)));
typedef float f32x4 __attribute__((ext_vector_type(4)));

constexpr int BK = 32;

#define GLD(g, l) __builtin_amdgcn_global_load_lds( \
    (const __attribute__((address_space(1))) void*)(g), \
    (__attribute__((address_space(3))) void*)(l), 16, 0, 0)

struct Ep {
  f16 *ha, *la, *hb, *lb;       // split-write targets (hi/lo pairs)
  float *fa, *fb, *fc, *fd;     // f32 writes (may alias reads, same idx only)
  const float *ra, *rb;         // f32 reads
  const float *bias, *bias2;    // per-column vectors
  float sAinv, sOut;            // 1/sigma_A for acc unscale; sigma for writes
};

enum { OP_Z0, OP_T, OP_V, OP_U, OP_ULAST, OP_QW, OP_PW, OP_G, OP_E };

// split write: hi = f16(v*s), lo = f16((v*s - hi) * 2048)
__device__ __forceinline__ void wsplit(f16* h, f16* l, size_t i, float v, float s) {
  const float vs = v * s;
  const f16 hi = (f16)vs;
  h[i] = hi;
  if (l) l[i] = (f16)((vs - (float)hi) * 2048.f);
}

// C = A @ Bt^T accumulated over NPH phases; N = K = 1024 fixed; M = gridDim.y*128.
// Phase order (NPH==3): (Ah,Bl), (Al,Bh), then acc *= 1/2048, then (Ah,Bh).
template <int MODE, int NPH>
__global__ __launch_bounds__(256) void gk(const f16* __restrict__ A0, const f16* __restrict__ B0,
                                          const f16* __restrict__ A1, const f16* __restrict__ B1,
                                          const f16* __restrict__ A2, const f16* __restrict__ B2,
                                          Ep ep) {
  __shared__ f16 As[128 * BK] __attribute__((aligned(16)));
  __shared__ f16 Bs[128 * BK] __attribute__((aligned(16)));
  const int tid = threadIdx.x;
  const int w = tid >> 6, lane = tid & 63;
  const int tm = blockIdx.y * 128, tn = blockIdx.x * 128;

  const int srow = w * 16 + (lane >> 2);
  const int scol = (lane & 3) * 8;
  f16* lA0 = As + w * 512;
  f16* lA1 = As + 2048 + w * 512;
  f16* lB0 = Bs + w * 512;
  f16* lB1 = Bs + 2048 + w * 512;

  const int wr = w >> 1, wc = w & 1;
  const int fr = lane & 15;
  const int kb = (lane >> 4) * 8;
  const int ao = (wr * 64 + fr) * BK + kb;
  const int bo = (wc * 64 + fr) * BK + kb;

  f32x4 acc[4][4] = {};

  const f16* PA[3] = {A0, A1, A2};
  const f16* PB[3] = {B0, B1, B2};
#pragma unroll
  for (int ph = 0; ph < NPH; ++ph) {
    const f16* gA0 = PA[ph] + (size_t)(tm + srow) * 1024 + scol;
    const f16* gA1 = gA0 + (size_t)64 * 1024;
    const f16* gB0 = PB[ph] + (size_t)(tn + srow) * 1024 + scol;
    const f16* gB1 = gB0 + (size_t)64 * 1024;
    for (int kt = 0; kt < 1024; kt += BK) {
      __syncthreads();
      GLD(gA0, lA0); GLD(gA1, lA1); GLD(gB0, lB0); GLD(gB1, lB1);
      gA0 += BK; gA1 += BK; gB0 += BK; gB1 += BK;
      __syncthreads();
      f16x8 af[4], bf[4];
#pragma unroll
      for (int i = 0; i < 4; i++) af[i] = *(const f16x8*)(As + ao + i * 16 * BK);
#pragma unroll
      for (int i = 0; i < 4; i++) bf[i] = *(const f16x8*)(Bs + bo + i * 16 * BK);
#pragma unroll
      for (int mi = 0; mi < 4; mi++)
#pragma unroll
        for (int ni = 0; ni < 4; ni++)
          acc[mi][ni] = __builtin_amdgcn_mfma_f32_16x16x32_f16(af[mi], bf[ni], acc[mi][ni], 0, 0, 0);
    }
    if (NPH == 3 && ph == 1) {
#pragma unroll
      for (int mi = 0; mi < 4; mi++)
#pragma unroll
        for (int ni = 0; ni < 4; ni++)
          acc[mi][ni] *= (1.f / 2048.f);
    }
  }

  // C/D layout: col = lane&15, row = (lane>>4)*4 + j  [m89]
  const int er = wr * 64 + ((lane >> 4) << 2);
  const int ec = wc * 64 + fr;
#pragma unroll
  for (int mi = 0; mi < 4; mi++)
#pragma unroll
    for (int ni = 0; ni < 4; ni++)
#pragma unroll
      for (int j = 0; j < 4; j++) {
        const int r = tm + er + mi * 16 + j;
        const int c = tn + ec + ni * 16;
        const size_t i = (size_t)r * 1024 + c;
        const float av = acc[mi][ni][j];
        if constexpr (MODE == OP_Z0) {
          const float z = av * ep.sAinv + ep.bias[c];     // z = x@Win^T + b_in
          const float r1 = z + 0.1f * ep.bias2[c];        // r1(0) = z + 0.1*b1
          ep.fa[i] = r1;                                  // R1f
          ep.fb[i] = 11.f * fmaxf(z, 0.f);                // Y = r2(0) = 11*relu(z)
          ep.fc[i] = 0.f;                                 // S1 = 0
          ep.fd[i] = 0.f;                                 // S2 = 0
          wsplit(ep.ha, ep.la, i, r1, ep.sOut);
        } else if constexpr (MODE == OP_T) {
          const float T = ep.ra[i] + 0.1f * av * ep.sAinv;  // T = r2 + 0.1*r1@W
          ep.fa[i] = T;                                     // X
          wsplit(ep.ha, ep.la, i, T, ep.sOut);
        } else if constexpr (MODE == OP_V) {
          const float T = ep.fa[i];
          const float v = (T + av * ep.sAinv * (1.f / 256.f)) * (1.f / 11.f); // v = (T + T@E)/11
          ep.fa[i] = v;                                     // X := v
          wsplit(ep.ha, ep.la, i, v, ep.sOut);
          const float pp = v + ep.ra[i];                    // p = v + s2
          wsplit(ep.hb, ep.lb, i, pp, ep.sOut);
        } else if constexpr (MODE == OP_U || MODE == OP_ULAST) {
          const float u = ep.ra[i] - 0.1f * av * ep.sAinv;  // u = r1 - 0.1*v@W^T
          const float q = u + ep.rb[i];                     // q = u + s1
          if constexpr (MODE == OP_U) {
            ep.fa[i] = q;                                   // R1f := q
            wsplit(ep.ha, ep.la, i, q, ep.sOut);
          } else {
            ep.fb[i] = -q;                                  // Y := u_out(3) = -q
          }
        } else if constexpr (MODE == OP_QW) {
          const float qW = av * ep.sAinv;                   // q@W
          const float vf = ep.ra[i];                        // v
          const float s2 = ep.fb[i];
          const float q = ep.rb[i];
          ep.fa[i] = 10.f * vf + 9.f * s2 + 10.f * fmaxf(-q, 0.f) - 0.1f * qW;  // r2'
          ep.fb[i] = -10.f * s2 - 11.f * vf + 0.1f * qW;                        // s2'
        } else if constexpr (MODE == OP_PW) {
          const float pW = av * ep.sAinv;                   // p@W^T
          const float s1 = ep.fb[i];
          const float q = ep.ra[i];
          const float u = q - s1;
          const float r1n = 0.1f * ep.bias[c] - s1 + 0.1f * pW;  // r1'
          ep.fa[i] = r1n;
          ep.fb[i] = -u - 0.1f * pW;                        // s1'
          wsplit(ep.ha, ep.la, i, r1n, ep.sOut);
        } else if constexpr (MODE == OP_G) {
          ep.fa[i] = av;                                    // G f32
          ep.ha[i] = (f16)av;                               // Gh
        } else if constexpr (MODE == OP_E) {
          constexpr float C1 = 0.01f / 11.f;
          ep.ha[i] = (f16)(256.f * (C1 * C1 * av - C1 * ep.ra[i]));  // E256
        }
      }
}

// x chunk: pad 784->1024, scale 16, split
__global__ __launch_bounds__(256) void xsplit(const float* __restrict__ src,
                                              f16* __restrict__ h, f16* __restrict__ l) {
  const size_t i = (size_t)blockIdx.x * 256 + threadIdx.x;
  const int k = (int)(i & 1023);
  const size_t m = i >> 10;
  const float v = (k < 784) ? src[m * 784 + k] : 0.f;
  const float vs = v * 16.f;
  const f16 hi = (f16)vs;
  h[i] = hi;
  l[i] = (f16)((vs - (float)hi) * 2048.f);
}

// Win: pad 784->1024, split (weight-style, scale 1)
__global__ __launch_bounds__(256) void wins(const float* __restrict__ src,
                                            f16* __restrict__ h, f16* __restrict__ l) {
  const size_t i = (size_t)blockIdx.x * 256 + threadIdx.x;
  const int k = (int)(i & 1023);
  const size_t m = i >> 10;
  const float v = (k < 784) ? src[m * 784 + k] : 0.f;
  const f16 hi = (f16)v;
  h[i] = hi;
  l[i] = (f16)((v - (float)hi) * 2048.f);
}

// 4 layer weights -> split direct + split transposed
__global__ __launch_bounds__(256) void wsplit4(const float* __restrict__ W0, const float* __restrict__ W1,
                                               const float* __restrict__ W2, const float* __restrict__ W3,
                                               f16* __restrict__ Wh, f16* __restrict__ Wl,
                                               f16* __restrict__ WTh, f16* __restrict__ WTl) {
  __shared__ float t[32][33];
  const int lz = blockIdx.z;
  const float* W = lz == 0 ? W0 : lz == 1 ? W1 : lz == 2 ? W2 : W3;
  const size_t off = (size_t)lz * 1024 * 1024;
  const int c0 = blockIdx.x * 32, r0 = blockIdx.y * 32;
  const int tx = threadIdx.x, ty = threadIdx.y;
#pragma unroll
  for (int i = ty; i < 32; i += 8) {
    const float v = W[(size_t)(r0 + i) * 1024 + c0 + tx];
    t[i][tx] = v;
    const f16 hi = (f16)v;
    Wh[off + (size_t)(r0 + i) * 1024 + c0 + tx] = hi;
    Wl[off + (size_t)(r0 + i) * 1024 + c0 + tx] = (f16)((v - (float)hi) * 2048.f);
  }
  __syncthreads();
#pragma unroll
  for (int i = ty; i < 32; i += 8) {
    const float v = t[tx][i];
    const f16 hi = (f16)v;
    WTh[off + (size_t)(c0 + i) * 1024 + r0 + tx] = hi;
    WTl[off + (size_t)(c0 + i) * 1024 + r0 + tx] = (f16)((v - (float)hi) * 2048.f);
  }
}

// logits = softmax(Y @ Wout^T + bout); one wave per row
__global__ __launch_bounds__(256) void out_softmax(const float* __restrict__ Yf,
                                                   const float* __restrict__ Wout,
                                                   const float* __restrict__ bo,
                                                   float* __restrict__ out) {
  const int row = blockIdx.x * 4 + (threadIdx.x >> 6);
  const int lane = threadIdx.x & 63;
  const float* u = Yf + (size_t)row * 1024;
  float p[10];
#pragma unroll
  for (int t = 0; t < 10; t++) p[t] = 0.f;
#pragma unroll
  for (int j = 0; j < 4; j++) {
    const int kbase = (j * 64 + lane) * 4;
    const float4 uv = *(const float4*)(u + kbase);
#pragma unroll
    for (int t = 0; t < 10; t++) {
      const float4 wv = *(const float4*)(Wout + t * 1024 + kbase);
      p[t] += uv.x * wv.x + uv.y * wv.y + uv.z * wv.z + uv.w * wv.w;
    }
  }
#pragma unroll
  for (int off = 32; off; off >>= 1)
#pragma unroll
    for (int t = 0; t < 10; t++) p[t] += __shfl_down(p[t], off);
  if (lane == 0) {
    float lg[10], m = -1e30f, s = 0.f;
#pragma unroll
    for (int t = 0; t < 10; t++) { lg[t] = p[t] + bo[t]; m = fmaxf(m, lg[t]); }
#pragma unroll
    for (int t = 0; t < 10; t++) { lg[t] = expf(lg[t] - m); s += lg[t]; }
    const float inv = 1.f / s;
    float* o = out + (size_t)row * 10;
#pragma unroll
    for (int t = 0; t < 10; t++) o[t] = lg[t] * inv;
  }
}

extern "C" void kernel_launch(void* const* d_in, const int* in_sizes, int n_in,
                              void* d_out, int out_size, void* d_ws, size_t ws_size,
                              hipStream_t stream) {
  const float* x = (const float*)d_in[0];
  const float* Win = (const float*)d_in[1];
  const float* bin = (const float*)d_in[2];
  const float* Wgt[4] = {(const float*)d_in[3], (const float*)d_in[5],
                         (const float*)d_in[7], (const float*)d_in[9]};
  const float* bl[4] = {(const float*)d_in[4], (const float*)d_in[6],
                        (const float*)d_in[8], (const float*)d_in[10]};
  const float* Wout = (const float*)d_in[11];
  const float* bout = (const float*)d_in[12];
  float* out = (float*)d_out;

  char* p = (char*)d_ws;
  auto take = [&](size_t n) {
    void* q = (void*)p;
    p += (n + 255) & ~(size_t)255;
    return q;
  };
  const size_t UU = (size_t)1024 * 1024;

  // fixed footprint (~50MB)
  f16* Wh = (f16*)take(4 * UU * 2);
  f16* Wl = (f16*)take(4 * UU * 2);
  f16* WTh = (f16*)take(4 * UU * 2);
  f16* WTl = (f16*)take(4 * UU * 2);
  f16* Winh = (f16*)take(UU * 2);
  f16* Winl = (f16*)take(UU * 2);
  f16* Eh = (f16*)take(4 * UU * 2);
  float* Gf = (float*)take(UU * 4);
  f16* Gh = (f16*)take(UU * 2);
  const size_t fixedB = (size_t)(p - (char*)d_ws);

  // chunk size: per-chunk bytes = Mc*1024*(5*4 + 8*2) = Mc*36KB (+ alignment slack)
  int Mc = 8192;
  while (Mc > 128 && fixedB + (size_t)Mc * 1024 * 36 + 8192 > ws_size) Mc >>= 1;
  if (fixedB + (size_t)Mc * 1024 * 36 + 8192 > ws_size) return;  // hopeless
  const size_t CF = (size_t)Mc * 1024;

  float* R1f = (float*)take(CF * 4);
  float* Xb = (float*)take(CF * 4);
  float* Yb = (float*)take(CF * 4);
  float* S1 = (float*)take(CF * 4);
  float* S2 = (float*)take(CF * 4);
  f16* P0h = (f16*)take(CF * 2); f16* P0l = (f16*)take(CF * 2);
  f16* P1h = (f16*)take(CF * 2); f16* P1l = (f16*)take(CF * 2);
  f16* P2h = (f16*)take(CF * 2); f16* P2l = (f16*)take(CF * 2);
  f16* P3h = (f16*)take(CF * 2); f16* P3l = (f16*)take(CF * 2);

  // ---- weight precompute ----
  wins<<<dim3((unsigned)(UU / 256)), 256, 0, stream>>>(Win, Winh, Winl);
  wsplit4<<<dim3(32, 32, 4), dim3(32, 8), 0, stream>>>(Wgt[0], Wgt[1], Wgt[2], Wgt[3],
                                                       Wh, Wl, WTh, WTl);
  for (int l = 0; l < 4; l++) {
    const f16 *wth = WTh + l * UU, *wtl = WTl + l * UU;
    Ep e{};
    e.fa = Gf; e.ha = Gh; e.sAinv = 1.f;
    gk<OP_G, 3><<<dim3(8, 8), 256, 0, stream>>>(wth, wtl, wtl, wth, wth, wth, e);
    Ep e2{};
    e2.ra = Gf; e2.ha = Eh + l * UU; e2.sAinv = 1.f;
    gk<OP_E, 1><<<dim3(8, 8), 256, 0, stream>>>(Gh, Gh, Gh, Gh, Gh, Gh, e2);
  }

  const float SIG[4] = {16.f, 2.f, 0.25f, 0.03125f};
  const int nch = 8192 / Mc;
  const dim3 gg(8, Mc / 128);

  for (int ch = 0; ch < nch; ++ch) {
    const size_t r0 = (size_t)ch * Mc;
    xsplit<<<dim3(Mc * 4), 256, 0, stream>>>(x + r0 * 784, P1h, P1l);
    {
      Ep e{};
      e.bias = bin; e.bias2 = bl[0];
      e.fa = R1f; e.fb = Yb; e.fc = S1; e.fd = S2;
      e.ha = P0h; e.la = P0l; e.sAinv = 1.f / 16.f; e.sOut = 16.f;
      gk<OP_Z0, 3><<<gg, 256, 0, stream>>>(P1h, Winl, P1l, Winh, P1h, Winh, e);
    }
    for (int l = 0; l < 4; l++) {
      const f16 *wh = Wh + l * UU, *wl = Wl + l * UU;
      const f16 *wth = WTh + l * UU, *wtl = WTl + l * UU;
      const float sl = SIG[l], sli = 1.f / sl;
      {  // G1: T = r2 + 0.1*r1@W
        Ep e{};
        e.ra = Yb; e.fa = Xb; e.ha = P1h; e.la = nullptr; e.sAinv = sli; e.sOut = sl;
        gk<OP_T, 3><<<gg, 256, 0, stream>>>(P0h, wtl, P0l, wth, P0h, wth, e);
      }
      {  // G2: v = (T + T@E)/11 ; p = v + s2
        Ep e{};
        e.fa = Xb; e.ra = S2; e.ha = P2h; e.la = P2l; e.hb = P3h; e.lb = P3l;
        e.sAinv = sli; e.sOut = sl;
        gk<OP_V, 1><<<gg, 256, 0, stream>>>(P1h, Eh + l * UU, P1h, Eh, P1h, Eh, e);
      }
      if (l < 3) {
        {  // G3: u = r1 - 0.1*v@W^T ; q = u + s1
          Ep e{};
          e.ra = R1f; e.rb = S1; e.fa = R1f; e.ha = P1h; e.la = P1l;
          e.sAinv = sli; e.sOut = sl;
          gk<OP_U, 3><<<gg, 256, 0, stream>>>(P2h, wl, P2l, wh, P2h, wh, e);
        }
        {  // G5: r2' , s2'  (needs q@W)
          Ep e{};
          e.ra = Xb; e.rb = R1f; e.fa = Yb; e.fb = S2; e.sAinv = sli;
          gk<OP_QW, 3><<<gg, 256, 0, stream>>>(P1h, wtl, P1l, wth, P1h, wth, e);
        }
        {  // G4: r1' , s1'  (needs p@W^T)
          Ep e{};
          e.ra = R1f; e.fb = S1; e.fa = R1f; e.bias = bl[l + 1];
          e.ha = P0h; e.la = P0l; e.sAinv = sli; e.sOut = SIG[l + 1];
          gk<OP_PW, 3><<<gg, 256, 0, stream>>>(P3h, wl, P3l, wh, P3h, wh, e);
        }
      } else {  // last layer: only u_out = -q
        Ep e{};
        e.ra = R1f; e.rb = S1; e.fb = Yb; e.sAinv = sli;
        gk<OP_ULAST, 3><<<gg, 256, 0, stream>>>(P2h, wl, P2l, wh, P2h, wh, e);
      }
    }
    out_softmax<<<dim3(Mc / 4), 256, 0, stream>>>(Yb, Wout, bout, out + r0 * 10);
  }
}

// Round 4
// 2422.591 us; speedup vs baseline: 1.4452x; 1.4452x over previous
//
#include <hip/hip_runtime.h>

typedef _Float16 f16;
typedef _Float16 f16x8 __attribute__((ext_vector_type(8)));
typedef float f32x4 __attribute__((ext_vector_type(4)));

#define GLD(g, l) __builtin_amdgcn_global_load_lds( \
    (const __attribute__((address_space(1))) void*)(g), \
    (__attribute__((address_space(3))) void*)(l), 16, 0, 0)

struct Ep {
  f16 *ha, *la, *hb, *lb;        // split writes
  float *fa, *fb;                // f32 writes
  const float *ra, *rb;          // f32 reads (rb may be null -> 0)
  const f16 *xh, *xl, *yh, *yl;  // split reads (reconstruct)
  const float *bias, *bias2;
  float sAinv, sOut, sX, sY;
};

enum { OP_Z0, OP_T, OP_V, OP_U, OP_ULAST, OP_QW, OP_PW, OP_G, OP_E };

// split write: hi = f16(v*s), lo = f16((v*s - hi) * 2048)
__device__ __forceinline__ void wsplit(f16* h, f16* l, size_t i, float v, float s) {
  const float vs = v * s;
  const f16 hi = (f16)vs;
  h[i] = hi;
  l[i] = (f16)((vs - (float)hi) * 2048.f);
}
__device__ __forceinline__ float rec(const f16* h, const f16* l, size_t i, float s) {
  return ((float)h[i] + (float)l[i] * (1.f / 2048.f)) * s;
}

// C = A@Bt^T, K=N=1024. TRI: A=(Ah+Al/2048), B=(Bh+Bl/2048), dual accumulators,
// 48 MFMA per barrier-pair, single pass over A/B. 1-D grid, XCD-chunked swizzle.
template <int MODE, int TRI>
__global__ __launch_bounds__(256, 2) void gk(const f16* __restrict__ Ah, const f16* __restrict__ Al,
                                             const f16* __restrict__ Bh, const f16* __restrict__ Bl,
                                             Ep ep) {
  __shared__ f16 As[2][4096] __attribute__((aligned(16)));
  __shared__ f16 Bs[2][4096] __attribute__((aligned(16)));
  const int tid = threadIdx.x;
  const int w = tid >> 6, lane = tid & 63;
  // XCD-chunked bijective swizzle (nwg % 8 == 0 always here)
  const unsigned nb = gridDim.x;
  unsigned bid = blockIdx.x;
  bid = (bid & 7) * (nb >> 3) + (bid >> 3);
  const int tn = (int)(bid & 7) * 128;
  const int tm = (int)(bid >> 3) * 128;

  const int srow = w * 16 + (lane >> 2);
  const int scol = (lane & 3) * 8;
  const size_t aoff = (size_t)(tm + srow) * 1024 + scol;
  const size_t boff = (size_t)(tn + srow) * 1024 + scol;
  const f16* gAh0 = Ah + aoff; const f16* gAh1 = gAh0 + (size_t)64 * 1024;
  const f16* gAl0 = Al + aoff; const f16* gAl1 = gAl0 + (size_t)64 * 1024;
  const f16* gBh0 = Bh + boff; const f16* gBh1 = gBh0 + (size_t)64 * 1024;
  const f16* gBl0 = Bl + boff; const f16* gBl1 = gBl0 + (size_t)64 * 1024;
  f16* lAh0 = &As[0][w * 512]; f16* lAh1 = &As[0][2048 + w * 512];
  f16* lAl0 = &As[1][w * 512]; f16* lAl1 = &As[1][2048 + w * 512];
  f16* lBh0 = &Bs[0][w * 512]; f16* lBh1 = &Bs[0][2048 + w * 512];
  f16* lBl0 = &Bs[1][w * 512]; f16* lBl1 = &Bs[1][2048 + w * 512];

  const int wr = w >> 1, wc = w & 1;
  const int fr = lane & 15;
  const int kb = (lane >> 4) * 8;
  const int ao = (wr * 64 + fr) * 32 + kb;
  const int bo = (wc * 64 + fr) * 32 + kb;

  f32x4 hi[4][4] = {};
  f32x4 lo[4][4] = {};

  for (int kt = 0; kt < 1024; kt += 32) {
    __syncthreads();
    GLD(gAh0, lAh0); GLD(gAh1, lAh1);
    GLD(gBh0, lBh0); GLD(gBh1, lBh1);
    if (TRI) {
      GLD(gAl0, lAl0); GLD(gAl1, lAl1);
      GLD(gBl0, lBl0); GLD(gBl1, lBl1);
    }
    gAh0 += 32; gAh1 += 32; gBh0 += 32; gBh1 += 32;
    if (TRI) { gAl0 += 32; gAl1 += 32; gBl0 += 32; gBl1 += 32; }
    __syncthreads();
    f16x8 ah[4], bh[4];
#pragma unroll
    for (int i = 0; i < 4; i++) ah[i] = *(const f16x8*)(&As[0][ao + i * 512]);
#pragma unroll
    for (int i = 0; i < 4; i++) bh[i] = *(const f16x8*)(&Bs[0][bo + i * 512]);
#pragma unroll
    for (int mi = 0; mi < 4; mi++)
#pragma unroll
      for (int ni = 0; ni < 4; ni++)
        hi[mi][ni] = __builtin_amdgcn_mfma_f32_16x16x32_f16(ah[mi], bh[ni], hi[mi][ni], 0, 0, 0);
    if (TRI) {
      f16x8 al[4], bl[4];
#pragma unroll
      for (int i = 0; i < 4; i++) al[i] = *(const f16x8*)(&As[1][ao + i * 512]);
#pragma unroll
      for (int i = 0; i < 4; i++) bl[i] = *(const f16x8*)(&Bs[1][bo + i * 512]);
#pragma unroll
      for (int mi = 0; mi < 4; mi++)
#pragma unroll
        for (int ni = 0; ni < 4; ni++)
          lo[mi][ni] = __builtin_amdgcn_mfma_f32_16x16x32_f16(ah[mi], bl[ni], lo[mi][ni], 0, 0, 0);
#pragma unroll
      for (int mi = 0; mi < 4; mi++)
#pragma unroll
        for (int ni = 0; ni < 4; ni++)
          lo[mi][ni] = __builtin_amdgcn_mfma_f32_16x16x32_f16(al[mi], bh[ni], lo[mi][ni], 0, 0, 0);
    }
  }

  // C/D layout: col = lane&15, row = (lane>>4)*4 + j  [m89]
  const int er = wr * 64 + ((lane >> 4) << 2);
  const int ec = wc * 64 + fr;
#pragma unroll
  for (int mi = 0; mi < 4; mi++)
#pragma unroll
    for (int ni = 0; ni < 4; ni++)
#pragma unroll
      for (int j = 0; j < 4; j++) {
        const int r = tm + er + mi * 16 + j;
        const int c = tn + ec + ni * 16;
        const size_t i = (size_t)r * 1024 + c;
        const float av = TRI ? (hi[mi][ni][j] + lo[mi][ni][j] * (1.f / 2048.f))
                             : hi[mi][ni][j];
        if constexpr (MODE == OP_Z0) {
          const float z = av * ep.sAinv + ep.bias[c];
          const float r1 = z + 0.1f * ep.bias2[c];
          ep.fb[i] = 11.f * fmaxf(z, 0.f);                 // Yb := r2(0)
          wsplit(ep.ha, ep.la, i, r1, ep.sOut);            // P0 := r1
        } else if constexpr (MODE == OP_T) {
          const float T = ep.ra[i] + 0.1f * av * ep.sAinv; // T = r2 + 0.1*r1@W
          wsplit(ep.ha, ep.la, i, T, ep.sOut);             // P1 := T
        } else if constexpr (MODE == OP_V) {
          const float T = rec(ep.xh, ep.xl, i, ep.sX);
          const float v = (T + av * ep.sAinv * (1.f / 256.f)) * (1.f / 11.f);
          wsplit(ep.ha, ep.la, i, v, ep.sOut);             // P2 := v
          const float pp = v + (ep.rb ? ep.rb[i] : 0.f);   // p = v + s2
          wsplit(ep.hb, ep.lb, i, pp, ep.sOut);            // P3 := p
        } else if constexpr (MODE == OP_U) {
          const float r1 = rec(ep.xh, ep.xl, i, ep.sX);
          const float u = r1 - 0.1f * av * ep.sAinv;       // u = r1 - 0.1*v@W^T
          const float q = u + (ep.rb ? ep.rb[i] : 0.f);    // q = u + s1
          wsplit(ep.ha, ep.la, i, q, ep.sOut);             // P1 := q
        } else if constexpr (MODE == OP_ULAST) {
          const float r1 = rec(ep.xh, ep.xl, i, ep.sX);
          const float u = r1 - 0.1f * av * ep.sAinv;
          const float q = u + (ep.rb ? ep.rb[i] : 0.f);
          ep.fb[i] = -q;                                   // Yb := logits
        } else if constexpr (MODE == OP_QW) {
          const float q = rec(ep.xh, ep.xl, i, ep.sX);
          const float v = rec(ep.yh, ep.yl, i, ep.sY);
          const float s2 = ep.rb ? ep.rb[i] : 0.f;
          const float qW = av * ep.sAinv;                  // q@W
          ep.fa[i] = 10.f * v + 9.f * s2 + 10.f * fmaxf(-q, 0.f) - 0.1f * qW;  // r2'
          ep.fb[i] = -10.f * s2 - 11.f * v + 0.1f * qW;                        // s2'
        } else if constexpr (MODE == OP_PW) {
          const float q = rec(ep.xh, ep.xl, i, ep.sX);
          const float s1 = ep.rb ? ep.rb[i] : 0.f;
          const float u = q - s1;
          const float pW = av * ep.sAinv;                  // p@W^T
          ep.fb[i] = -u - 0.1f * pW;                       // s1'
          wsplit(ep.ha, ep.la, i, 0.1f * ep.bias[c] - s1 + 0.1f * pW, ep.sOut);  // P0 := r1'
        } else if constexpr (MODE == OP_G) {
          ep.fa[i] = av;
          ep.ha[i] = (f16)av;
        } else if constexpr (MODE == OP_E) {
          constexpr float C1 = 0.01f / 11.f;
          ep.ha[i] = (f16)(256.f * (C1 * C1 * av - C1 * ep.ra[i]));  // E*256
        }
      }
}

// x chunk: pad 784->1024, scale 16, split
__global__ __launch_bounds__(256) void xsplit(const float* __restrict__ src,
                                              f16* __restrict__ h, f16* __restrict__ l) {
  const size_t i = (size_t)blockIdx.x * 256 + threadIdx.x;
  const int k = (int)(i & 1023);
  const size_t m = i >> 10;
  const float v = (k < 784) ? src[m * 784 + k] : 0.f;
  const float vs = v * 16.f;
  const f16 hi = (f16)vs;
  h[i] = hi;
  l[i] = (f16)((vs - (float)hi) * 2048.f);
}

// Win: pad 784->1024, split
__global__ __launch_bounds__(256) void wins(const float* __restrict__ src,
                                            f16* __restrict__ h, f16* __restrict__ l) {
  const size_t i = (size_t)blockIdx.x * 256 + threadIdx.x;
  const int k = (int)(i & 1023);
  const size_t m = i >> 10;
  const float v = (k < 784) ? src[m * 784 + k] : 0.f;
  const f16 hi = (f16)v;
  h[i] = hi;
  l[i] = (f16)((v - (float)hi) * 2048.f);
}

// 4 layer weights -> split direct + split transposed
__global__ __launch_bounds__(256) void wsplit4(const float* __restrict__ W0, const float* __restrict__ W1,
                                               const float* __restrict__ W2, const float* __restrict__ W3,
                                               f16* __restrict__ Wh, f16* __restrict__ Wl,
                                               f16* __restrict__ WTh, f16* __restrict__ WTl) {
  __shared__ float t[32][33];
  const int lz = blockIdx.z;
  const float* W = lz == 0 ? W0 : lz == 1 ? W1 : lz == 2 ? W2 : W3;
  const size_t off = (size_t)lz * 1024 * 1024;
  const int c0 = blockIdx.x * 32, r0 = blockIdx.y * 32;
  const int tx = threadIdx.x, ty = threadIdx.y;
#pragma unroll
  for (int i = ty; i < 32; i += 8) {
    const float v = W[(size_t)(r0 + i) * 1024 + c0 + tx];
    t[i][tx] = v;
    const f16 hi = (f16)v;
    Wh[off + (size_t)(r0 + i) * 1024 + c0 + tx] = hi;
    Wl[off + (size_t)(r0 + i) * 1024 + c0 + tx] = (f16)((v - (float)hi) * 2048.f);
  }
  __syncthreads();
#pragma unroll
  for (int i = ty; i < 32; i += 8) {
    const float v = t[tx][i];
    const f16 hi = (f16)v;
    WTh[off + (size_t)(c0 + i) * 1024 + r0 + tx] = hi;
    WTl[off + (size_t)(c0 + i) * 1024 + r0 + tx] = (f16)((v - (float)hi) * 2048.f);
  }
}

// logits = softmax(Y @ Wout^T + bout); one wave per row
__global__ __launch_bounds__(256) void out_softmax(const float* __restrict__ Yf,
                                                   const float* __restrict__ Wout,
                                                   const float* __restrict__ bo,
                                                   float* __restrict__ out) {
  const int row = blockIdx.x * 4 + (threadIdx.x >> 6);
  const int lane = threadIdx.x & 63;
  const float* u = Yf + (size_t)row * 1024;
  float p[10];
#pragma unroll
  for (int t = 0; t < 10; t++) p[t] = 0.f;
#pragma unroll
  for (int j = 0; j < 4; j++) {
    const int kbase = (j * 64 + lane) * 4;
    const float4 uv = *(const float4*)(u + kbase);
#pragma unroll
    for (int t = 0; t < 10; t++) {
      const float4 wv = *(const float4*)(Wout + t * 1024 + kbase);
      p[t] += uv.x * wv.x + uv.y * wv.y + uv.z * wv.z + uv.w * wv.w;
    }
  }
#pragma unroll
  for (int off = 32; off; off >>= 1)
#pragma unroll
    for (int t = 0; t < 10; t++) p[t] += __shfl_down(p[t], off);
  if (lane == 0) {
    float lg[10], m = -1e30f, s = 0.f;
#pragma unroll
    for (int t = 0; t < 10; t++) { lg[t] = p[t] + bo[t]; m = fmaxf(m, lg[t]); }
#pragma unroll
    for (int t = 0; t < 10; t++) { lg[t] = expf(lg[t] - m); s += lg[t]; }
    const float inv = 1.f / s;
    float* o = out + (size_t)row * 10;
#pragma unroll
    for (int t = 0; t < 10; t++) o[t] = lg[t] * inv;
  }
}

extern "C" void kernel_launch(void* const* d_in, const int* in_sizes, int n_in,
                              void* d_out, int out_size, void* d_ws, size_t ws_size,
                              hipStream_t stream) {
  const float* x = (const float*)d_in[0];
  const float* Win = (const float*)d_in[1];
  const float* bin = (const float*)d_in[2];
  const float* Wgt[4] = {(const float*)d_in[3], (const float*)d_in[5],
                         (const float*)d_in[7], (const float*)d_in[9]};
  const float* bl[4] = {(const float*)d_in[4], (const float*)d_in[6],
                        (const float*)d_in[8], (const float*)d_in[10]};
  const float* Wout = (const float*)d_in[11];
  const float* bout = (const float*)d_in[12];
  float* out = (float*)d_out;

  char* p = (char*)d_ws;
  auto take = [&](size_t n) {
    void* q = (void*)p;
    p += (n + 255) & ~(size_t)255;
    return q;
  };
  const size_t UU = (size_t)1024 * 1024;

  // fixed footprint (~48MB)
  f16* Wh = (f16*)take(4 * UU * 2);
  f16* Wl = (f16*)take(4 * UU * 2);
  f16* WTh = (f16*)take(4 * UU * 2);
  f16* WTl = (f16*)take(4 * UU * 2);
  f16* Winh = (f16*)take(UU * 2);
  f16* Winl = (f16*)take(UU * 2);
  f16* Eh = (f16*)take(4 * UU * 2);
  float* Gf = (float*)take(UU * 4);
  f16* Gh = (f16*)take(UU * 2);
  const size_t fixedB = (size_t)(p - (char*)d_ws);

  // per-chunk bytes = Mc*1024*(3*4 + 8*2) = Mc*28KB
  int Mc = 8192;
  while (Mc > 128 && fixedB + (size_t)Mc * 1024 * 28 + 8192 > ws_size) Mc >>= 1;
  if (fixedB + (size_t)Mc * 1024 * 28 + 8192 > ws_size) return;
  const size_t CF = (size_t)Mc * 1024;

  float* Yb = (float*)take(CF * 4);
  float* S1 = (float*)take(CF * 4);
  float* S2 = (float*)take(CF * 4);
  f16* P0h = (f16*)take(CF * 2); f16* P0l = (f16*)take(CF * 2);
  f16* P1h = (f16*)take(CF * 2); f16* P1l = (f16*)take(CF * 2);
  f16* P2h = (f16*)take(CF * 2); f16* P2l = (f16*)take(CF * 2);
  f16* P3h = (f16*)take(CF * 2); f16* P3l = (f16*)take(CF * 2);

  // ---- weight precompute ----
  wins<<<dim3((unsigned)(UU / 256)), 256, 0, stream>>>(Win, Winh, Winl);
  wsplit4<<<dim3(32, 32, 4), dim3(32, 8), 0, stream>>>(Wgt[0], Wgt[1], Wgt[2], Wgt[3],
                                                       Wh, Wl, WTh, WTl);
  for (int l = 0; l < 4; l++) {
    const f16 *wth = WTh + l * UU, *wtl = WTl + l * UU;
    Ep e{};
    e.fa = Gf; e.ha = Gh; e.sAinv = 1.f;
    gk<OP_G, 1><<<dim3(64), 256, 0, stream>>>(wth, wtl, wth, wtl, e);
    Ep e2{};
    e2.ra = Gf; e2.ha = Eh + l * UU; e2.sAinv = 1.f;
    gk<OP_E, 0><<<dim3(64), 256, 0, stream>>>(Gh, Gh, Gh, Gh, e2);
  }

  const float SIG[5] = {16.f, 2.f, 0.25f, 0.03125f, 1.f};
  const int nch = 8192 / Mc;
  const dim3 gg((unsigned)(Mc / 128) * 8);

  for (int ch = 0; ch < nch; ++ch) {
    const size_t r0 = (size_t)ch * Mc;
    xsplit<<<dim3(Mc * 4), 256, 0, stream>>>(x + r0 * 784, P1h, P1l);
    {
      Ep e{};
      e.bias = bin; e.bias2 = bl[0];
      e.fb = Yb; e.ha = P0h; e.la = P0l;
      e.sAinv = 1.f / 16.f; e.sOut = 16.f;
      gk<OP_Z0, 1><<<gg, 256, 0, stream>>>(P1h, P1l, Winh, Winl, e);
    }
    for (int l = 0; l < 4; l++) {
      const f16 *wh = Wh + l * UU, *wl = Wl + l * UU;
      const f16 *wth = WTh + l * UU, *wtl = WTl + l * UU;
      const f16* el = Eh + l * UU;
      const float sl = SIG[l], sli = 1.f / sl;
      const bool zs = (l == 0);
      {  // T = r2 + 0.1*r1@W  -> P1
        Ep e{};
        e.ra = Yb; e.ha = P1h; e.la = P1l; e.sAinv = sli; e.sOut = sl;
        gk<OP_T, 1><<<gg, 256, 0, stream>>>(P0h, P0l, wth, wtl, e);
      }
      {  // v = (T + T@E)/11 -> P2 ; p = v + s2 -> P3
        Ep e{};
        e.xh = P1h; e.xl = P1l; e.sX = sli; e.rb = zs ? nullptr : S2;
        e.ha = P2h; e.la = P2l; e.hb = P3h; e.lb = P3l;
        e.sAinv = sli; e.sOut = sl;
        gk<OP_V, 0><<<gg, 256, 0, stream>>>(P1h, P1h, el, el, e);
      }
      if (l < 3) {
        {  // u = r1 - 0.1*v@W^T ; q = u + s1 -> P1
          Ep e{};
          e.xh = P0h; e.xl = P0l; e.sX = sli; e.rb = zs ? nullptr : S1;
          e.ha = P1h; e.la = P1l; e.sAinv = sli; e.sOut = sl;
          gk<OP_U, 1><<<gg, 256, 0, stream>>>(P2h, P2l, wh, wl, e);
        }
        {  // r2' -> Yb ; s2' -> S2  (needs q@W)
          Ep e{};
          e.xh = P1h; e.xl = P1l; e.sX = sli;
          e.yh = P2h; e.yl = P2l; e.sY = sli;
          e.rb = zs ? nullptr : S2;
          e.fa = Yb; e.fb = S2; e.sAinv = sli;
          gk<OP_QW, 1><<<gg, 256, 0, stream>>>(P1h, P1l, wth, wtl, e);
        }
        {  // r1' -> P0 ; s1' -> S1  (needs p@W^T)
          Ep e{};
          e.xh = P1h; e.xl = P1l; e.sX = sli; e.rb = zs ? nullptr : S1;
          e.fb = S1; e.bias = bl[l + 1];
          e.ha = P0h; e.la = P0l; e.sAinv = sli; e.sOut = SIG[l + 1];
          gk<OP_PW, 1><<<gg, 256, 0, stream>>>(P3h, P3l, wh, wl, e);
        }
      } else {  // last layer: logits = -q -> Yb
        Ep e{};
        e.xh = P0h; e.xl = P0l; e.sX = sli; e.rb = S1;
        e.fb = Yb; e.sAinv = sli;
        gk<OP_ULAST, 1><<<gg, 256, 0, stream>>>(P2h, P2l, wh, wl, e);
      }
    }
    out_softmax<<<dim3(Mc / 4), 256, 0, stream>>>(Yb, Wout, bout, out + r0 * 10);
  }
}

// Round 5
// 2048.005 us; speedup vs baseline: 1.7095x; 1.1829x over previous
//
#include <hip/hip_runtime.h>

typedef _Float16 f16;
typedef _Float16 f16x8 __attribute__((ext_vector_type(8)));
typedef float f32x4 __attribute__((ext_vector_type(4)));

#define GLD(g, l) __builtin_amdgcn_global_load_lds( \
    (const __attribute__((address_space(1))) void*)(g), \
    (__attribute__((address_space(3))) void*)(l), 16, 0, 0)

struct Ep {
  f16 *ha, *la, *hb, *lb;        // split write targets
  float *fa, *fb;                // f32 writes
  const float *ra, *rb;          // f32 reads (null -> 0); WPT: W0,W1
  const f16 *xh, *xl, *yh, *yl;  // split reads (reconstruct)
  const f16 *a2, *b2;            // VNEW 4th stream (r2 rows, E cols)
  const f16 *b3h, *b3l;          // QP second-half B
  const float *bias, *bias2;     // bias vectors; WPT: W2,W3
  float sAinv, sOut, sX, sY;
  int Mh;
};

enum { OPX_Z0, OPX_VN, OPX_U, OPX_UL, OPX_QP, OPX_G, OPX_E, OPX_WPT };

__device__ __forceinline__ void wsplit(f16* h, f16* l, size_t i, float v, float s) {
  const float vs = v * s;
  const f16 hi = (f16)vs;
  h[i] = hi;
  l[i] = (f16)((vs - (float)hi) * 2048.f);
}
__device__ __forceinline__ float rec(const f16* h, const f16* l, size_t i, float s) {
  return ((float)h[i] + (float)l[i] * (1.f / 2048.f)) * s;
}

// C = A@Bt^T, K=N=1024, 128x128 tiles, BK=32, 4 waves.
// NS=1: hi only. NS=3: TRI split (hi + cross terms into lo bank).
// NS=4: TRI + extra single stream (a2@b2^T) accumulated into lo bank.
// gridDim.y = layer (offsets A/B/outputs by y*zs). XCD-chunked swizzle on x.
template <int MODE, int NS>
__global__ __launch_bounds__(256, 2) void gk(const f16* __restrict__ Ah, const f16* __restrict__ Al,
                                             const f16* __restrict__ Bh, const f16* __restrict__ Bl,
                                             size_t zs, Ep ep) {
  __shared__ f16 AsH[4096] __attribute__((aligned(16)));
  __shared__ f16 BsH[4096] __attribute__((aligned(16)));
  __shared__ f16 AsL[NS >= 3 ? 4096 : 16] __attribute__((aligned(16)));
  __shared__ f16 BsL[NS >= 3 ? 4096 : 16] __attribute__((aligned(16)));
  __shared__ f16 As2[NS == 4 ? 4096 : 16] __attribute__((aligned(16)));
  __shared__ f16 Bs2[NS == 4 ? 4096 : 16] __attribute__((aligned(16)));
  const int tid = threadIdx.x;
  const int w = tid >> 6, lane = tid & 63;
  const unsigned nb = gridDim.x;
  unsigned bid = blockIdx.x;
  bid = (bid & 7) * (nb >> 3) + (bid >> 3);   // XCD-chunked, bijective (nb%8==0)
  const int tn = (int)(bid & 7) * 128;
  const int tm = (int)(bid >> 3) * 128;
  const int ly = blockIdx.y;
  const size_t zo = (size_t)ly * zs;

  const f16* Bhp = Bh;
  const f16* Blp = Bl;
  if constexpr (MODE == OPX_QP) {
    if (tm >= ep.Mh) { Bhp = ep.b3h; Blp = ep.b3l; }
  }

  const int srow = w * 16 + (lane >> 2);
  const int scol = (lane & 3) * 8;
  const size_t aoff = zo + (size_t)(tm + srow) * 1024 + scol;
  const size_t boff = zo + (size_t)(tn + srow) * 1024 + scol;
  const f16* gAh0 = Ah + aoff; const f16* gAh1 = gAh0 + 65536;
  const f16* gBh0 = Bhp + boff; const f16* gBh1 = gBh0 + 65536;
  const f16 *gAl0 = nullptr, *gAl1 = nullptr, *gBl0 = nullptr, *gBl1 = nullptr;
  const f16 *gA20 = nullptr, *gA21 = nullptr, *gB20 = nullptr, *gB21 = nullptr;
  if constexpr (NS >= 3) {
    gAl0 = Al + aoff; gAl1 = gAl0 + 65536;
    gBl0 = Blp + boff; gBl1 = gBl0 + 65536;
  }
  if constexpr (NS == 4) {
    gA20 = ep.a2 + (size_t)(tm + srow) * 1024 + scol; gA21 = gA20 + 65536;
    gB20 = ep.b2 + (size_t)(tn + srow) * 1024 + scol; gB21 = gB20 + 65536;
  }
  f16* dAh0 = AsH + w * 512; f16* dAh1 = AsH + 2048 + w * 512;
  f16* dBh0 = BsH + w * 512; f16* dBh1 = BsH + 2048 + w * 512;
  f16* dAl0 = AsL + w * 512; f16* dAl1 = AsL + 2048 + w * 512;
  f16* dBl0 = BsL + w * 512; f16* dBl1 = BsL + 2048 + w * 512;
  f16* dA20 = As2 + w * 512; f16* dA21 = As2 + 2048 + w * 512;
  f16* dB20 = Bs2 + w * 512; f16* dB21 = Bs2 + 2048 + w * 512;

  const int wr = w >> 1, wc = w & 1;
  const int fr = lane & 15;
  const int kb = (lane >> 4) * 8;
  const int ao = (wr * 64 + fr) * 32 + kb;
  const int bo = (wc * 64 + fr) * 32 + kb;

  f32x4 hi[4][4] = {};
  f32x4 lo[4][4] = {};

  for (int kt = 0; kt < 1024; kt += 32) {
    __syncthreads();
    GLD(gAh0, dAh0); GLD(gAh1, dAh1);
    GLD(gBh0, dBh0); GLD(gBh1, dBh1);
    if constexpr (NS >= 3) {
      GLD(gAl0, dAl0); GLD(gAl1, dAl1);
      GLD(gBl0, dBl0); GLD(gBl1, dBl1);
    }
    if constexpr (NS == 4) {
      GLD(gA20, dA20); GLD(gA21, dA21);
      GLD(gB20, dB20); GLD(gB21, dB21);
    }
    gAh0 += 32; gAh1 += 32; gBh0 += 32; gBh1 += 32;
    if constexpr (NS >= 3) { gAl0 += 32; gAl1 += 32; gBl0 += 32; gBl1 += 32; }
    if constexpr (NS == 4) { gA20 += 32; gA21 += 32; gB20 += 32; gB21 += 32; }
    __syncthreads();
    f16x8 ah[4], bh[4];
#pragma unroll
    for (int i = 0; i < 4; i++) ah[i] = *(const f16x8*)(AsH + ao + i * 512);
#pragma unroll
    for (int i = 0; i < 4; i++) bh[i] = *(const f16x8*)(BsH + bo + i * 512);
#pragma unroll
    for (int mi = 0; mi < 4; mi++)
#pragma unroll
      for (int ni = 0; ni < 4; ni++)
        hi[mi][ni] = __builtin_amdgcn_mfma_f32_16x16x32_f16(ah[mi], bh[ni], hi[mi][ni], 0, 0, 0);
    if constexpr (NS >= 3) {
      f16x8 bl2[4];
#pragma unroll
      for (int i = 0; i < 4; i++) bl2[i] = *(const f16x8*)(BsL + bo + i * 512);
#pragma unroll
      for (int mi = 0; mi < 4; mi++)
#pragma unroll
        for (int ni = 0; ni < 4; ni++)
          lo[mi][ni] = __builtin_amdgcn_mfma_f32_16x16x32_f16(ah[mi], bl2[ni], lo[mi][ni], 0, 0, 0);
      f16x8 al2[4];
#pragma unroll
      for (int i = 0; i < 4; i++) al2[i] = *(const f16x8*)(AsL + ao + i * 512);
#pragma unroll
      for (int mi = 0; mi < 4; mi++)
#pragma unroll
        for (int ni = 0; ni < 4; ni++)
          lo[mi][ni] = __builtin_amdgcn_mfma_f32_16x16x32_f16(al2[mi], bh[ni], lo[mi][ni], 0, 0, 0);
    }
    if constexpr (NS == 4) {
      f16x8 a2f[4], b2f[4];
#pragma unroll
      for (int i = 0; i < 4; i++) a2f[i] = *(const f16x8*)(As2 + ao + i * 512);
#pragma unroll
      for (int i = 0; i < 4; i++) b2f[i] = *(const f16x8*)(Bs2 + bo + i * 512);
#pragma unroll
      for (int mi = 0; mi < 4; mi++)
#pragma unroll
        for (int ni = 0; ni < 4; ni++)
          lo[mi][ni] = __builtin_amdgcn_mfma_f32_16x16x32_f16(a2f[mi], b2f[ni], lo[mi][ni], 0, 0, 0);
    }
  }

  // C/D layout: col = lane&15, row = (lane>>4)*4 + j
  const int er = wr * 64 + ((lane >> 4) << 2);
  const int ec = wc * 64 + fr;
#pragma unroll
  for (int mi = 0; mi < 4; mi++)
#pragma unroll
    for (int ni = 0; ni < 4; ni++)
#pragma unroll
      for (int j = 0; j < 4; j++) {
        const int r = tm + er + mi * 16 + j;
        const int c = tn + ec + ni * 16;
        const size_t i = (size_t)r * 1024 + c;
        float av = hi[mi][ni][j];
        if constexpr (NS >= 3) av += lo[mi][ni][j] * (1.f / 2048.f);
        if constexpr (MODE == OPX_Z0) {
          const float z = av * ep.sAinv + ep.bias[c];
          wsplit(ep.ha, ep.la, i, z + 0.1f * ep.bias2[c], ep.sOut);  // r1(0)
          wsplit(ep.hb, ep.lb, i, 11.f * fmaxf(z, 0.f), ep.sOut);   // r2(0)
        } else if constexpr (MODE == OPX_VN) {
          // av = sl*(r1@Wp + 10*r2@E)  (r2@E came in via lo bank, E stored x20480)
          const float r2v = rec(ep.xh, ep.xl, i, ep.sX);
          const float v = (r2v + 0.1f * av * ep.sAinv) * (1.f / 11.f);
          wsplit(ep.ha, ep.la, i, v, ep.sOut);                       // v
          if (ep.hb) wsplit(ep.hb, ep.lb, i, v + (ep.rb ? ep.rb[i] : 0.f), ep.sOut);  // p = v+s2
        } else if constexpr (MODE == OPX_U) {
          const float r1 = rec(ep.xh, ep.xl, i, ep.sX);
          const float u = r1 - 0.1f * av * ep.sAinv;
          wsplit(ep.ha, ep.la, i, u + (ep.rb ? ep.rb[i] : 0.f), ep.sOut);  // q
        } else if constexpr (MODE == OPX_UL) {
          const float r1 = rec(ep.xh, ep.xl, i, ep.sX);
          const float u = r1 - 0.1f * av * ep.sAinv;
          ep.fb[i] = -(u + ep.rb[i]);                                // logits
        } else if constexpr (MODE == OPX_QP) {
          const bool qside = (r < ep.Mh);
          const size_t il = (size_t)(qside ? r : r - ep.Mh) * 1024 + c;
          const float q = rec(ep.xh, ep.xl, il, ep.sX);
          const float wv = av * ep.sAinv;
          if (qside) {                                               // wv = q@W
            const float v = rec(ep.yh, ep.yl, il, ep.sY);
            const float s2 = ep.rb ? ep.rb[il] : 0.f;
            wsplit(ep.ha, ep.la, il,
                   10.f * v + 9.f * s2 + 10.f * fmaxf(-q, 0.f) - 0.1f * wv, ep.sOut);  // r2'
            ep.fb[il] = -10.f * s2 - 11.f * v + 0.1f * wv;           // s2'
          } else {                                                   // wv = p@W^T
            const float s1 = ep.ra ? ep.ra[il] : 0.f;
            const float u = q - s1;
            ep.fa[il] = -u - 0.1f * wv;                              // s1'
            wsplit(ep.hb, ep.lb, il, 0.1f * ep.bias[c] - s1 + 0.1f * wv, ep.sOut);  // r1'
          }
        } else if constexpr (MODE == OPX_G) {
          ep.fa[zo + i] = av;
          ep.ha[zo + i] = (f16)av;
        } else if constexpr (MODE == OPX_E) {
          constexpr float C1 = 0.01f / 11.f;
          ep.ha[zo + i] = (f16)(20480.f * (C1 * C1 * av - C1 * ep.ra[zo + i]));  // E*20480
        } else if constexpr (MODE == OPX_WPT) {
          const float* Wf = ly == 0 ? ep.ra : ly == 1 ? ep.rb : ly == 2 ? ep.bias : ep.bias2;
          wsplit(ep.ha, ep.la, zo + i, Wf[(size_t)c * 1024 + r] + av * (1.f / 20480.f), 1.f);
        }
      }
}

// x chunk: pad 784->1024, scale 16, split
__global__ __launch_bounds__(256) void xsplit(const float* __restrict__ src,
                                              f16* __restrict__ h, f16* __restrict__ l) {
  const size_t i = (size_t)blockIdx.x * 256 + threadIdx.x;
  const int k = (int)(i & 1023);
  const size_t m = i >> 10;
  const float v = (k < 784) ? src[m * 784 + k] : 0.f;
  const float vs = v * 16.f;
  const f16 hi = (f16)vs;
  h[i] = hi;
  l[i] = (f16)((vs - (float)hi) * 2048.f);
}

// Win: pad 784->1024, split
__global__ __launch_bounds__(256) void wins(const float* __restrict__ src,
                                            f16* __restrict__ h, f16* __restrict__ l) {
  const size_t i = (size_t)blockIdx.x * 256 + threadIdx.x;
  const int k = (int)(i & 1023);
  const size_t m = i >> 10;
  const float v = (k < 784) ? src[m * 784 + k] : 0.f;
  const f16 hi = (f16)v;
  h[i] = hi;
  l[i] = (f16)((v - (float)hi) * 2048.f);
}

// 4 layer weights -> split direct + split transposed
__global__ __launch_bounds__(256) void wsplit4(const float* __restrict__ W0, const float* __restrict__ W1,
                                               const float* __restrict__ W2, const float* __restrict__ W3,
                                               f16* __restrict__ Wh, f16* __restrict__ Wl,
                                               f16* __restrict__ WTh, f16* __restrict__ WTl) {
  __shared__ float t[32][33];
  const int lz = blockIdx.z;
  const float* W = lz == 0 ? W0 : lz == 1 ? W1 : lz == 2 ? W2 : W3;
  const size_t off = (size_t)lz * 1024 * 1024;
  const int c0 = blockIdx.x * 32, r0 = blockIdx.y * 32;
  const int tx = threadIdx.x, ty = threadIdx.y;
#pragma unroll
  for (int i = ty; i < 32; i += 8) {
    const float v = W[(size_t)(r0 + i) * 1024 + c0 + tx];
    t[i][tx] = v;
    const f16 hi = (f16)v;
    Wh[off + (size_t)(r0 + i) * 1024 + c0 + tx] = hi;
    Wl[off + (size_t)(r0 + i) * 1024 + c0 + tx] = (f16)((v - (float)hi) * 2048.f);
  }
  __syncthreads();
#pragma unroll
  for (int i = ty; i < 32; i += 8) {
    const float v = t[tx][i];
    const f16 hi = (f16)v;
    WTh[off + (size_t)(c0 + i) * 1024 + r0 + tx] = hi;
    WTl[off + (size_t)(c0 + i) * 1024 + r0 + tx] = (f16)((v - (float)hi) * 2048.f);
  }
}

// logits = softmax(Y @ Wout^T + bout); one wave per row
__global__ __launch_bounds__(256) void out_softmax(const float* __restrict__ Yf,
                                                   const float* __restrict__ Wout,
                                                   const float* __restrict__ bo,
                                                   float* __restrict__ out) {
  const int row = blockIdx.x * 4 + (threadIdx.x >> 6);
  const int lane = threadIdx.x & 63;
  const float* u = Yf + (size_t)row * 1024;
  float p[10];
#pragma unroll
  for (int t = 0; t < 10; t++) p[t] = 0.f;
#pragma unroll
  for (int j = 0; j < 4; j++) {
    const int kbase = (j * 64 + lane) * 4;
    const float4 uv = *(const float4*)(u + kbase);
#pragma unroll
    for (int t = 0; t < 10; t++) {
      const float4 wv = *(const float4*)(Wout + t * 1024 + kbase);
      p[t] += uv.x * wv.x + uv.y * wv.y + uv.z * wv.z + uv.w * wv.w;
    }
  }
#pragma unroll
  for (int off = 32; off; off >>= 1)
#pragma unroll
    for (int t = 0; t < 10; t++) p[t] += __shfl_down(p[t], off);
  if (lane == 0) {
    float lg[10], m = -1e30f, s = 0.f;
#pragma unroll
    for (int t = 0; t < 10; t++) { lg[t] = p[t] + bo[t]; m = fmaxf(m, lg[t]); }
#pragma unroll
    for (int t = 0; t < 10; t++) { lg[t] = expf(lg[t] - m); s += lg[t]; }
    const float inv = 1.f / s;
    float* o = out + (size_t)row * 10;
#pragma unroll
    for (int t = 0; t < 10; t++) o[t] = lg[t] * inv;
  }
}

extern "C" void kernel_launch(void* const* d_in, const int* in_sizes, int n_in,
                              void* d_out, int out_size, void* d_ws, size_t ws_size,
                              hipStream_t stream) {
  const float* x = (const float*)d_in[0];
  const float* Win = (const float*)d_in[1];
  const float* bin = (const float*)d_in[2];
  const float* Wgt[4] = {(const float*)d_in[3], (const float*)d_in[5],
                         (const float*)d_in[7], (const float*)d_in[9]};
  const float* bl[4] = {(const float*)d_in[4], (const float*)d_in[6],
                        (const float*)d_in[8], (const float*)d_in[10]};
  const float* Wout = (const float*)d_in[11];
  const float* bout = (const float*)d_in[12];
  float* out = (float*)d_out;

  char* p = (char*)d_ws;
  auto take = [&](size_t n) {
    void* q = (void*)p;
    p += (n + 255) & ~(size_t)255;
    return q;
  };
  const size_t UU = (size_t)1024 * 1024;

  // persistent weights (~60MB)
  f16* Wh = (f16*)take(4 * UU * 2);
  f16* Wl = (f16*)take(4 * UU * 2);
  f16* WTh = (f16*)take(4 * UU * 2);
  f16* WTl = (f16*)take(4 * UU * 2);
  f16* Winh = (f16*)take(UU * 2);
  f16* Winl = (f16*)take(UU * 2);
  f16* WpTh = (f16*)take(4 * UU * 2);
  f16* WpTl = (f16*)take(4 * UU * 2);
  f16* E2 = (f16*)take(4 * UU * 2);
  const size_t fixedB = (size_t)(p - (char*)d_ws);

  // per-chunk arena = Mc*1024*28 bytes; Mc>=1024 so the G/Gh scratch (24MB) aliases inside
  int Mc = 8192;
  while (Mc > 1024 && fixedB + (size_t)Mc * 1024 * 28 + 65536 > ws_size) Mc >>= 1;
  if (fixedB + (size_t)Mc * 1024 * 28 + 65536 > ws_size) return;
  const size_t CF = (size_t)Mc * 1024;

  float* S1 = (float*)take(CF * 4);
  float* S2 = (float*)take(CF * 4);
  f16* P0h = (f16*)take(CF * 2); f16* P0l = (f16*)take(CF * 2);
  f16* P2h = (f16*)take(CF * 2); f16* P2l = (f16*)take(CF * 2);
  f16* R2h = (f16*)take(CF * 2); f16* R2l = (f16*)take(CF * 2);
  f16* Qh = (f16*)take(CF * 4);  // 2*CF elems: [0,CF)=q, [CF,2CF)=p
  f16* Ql = (f16*)take(CF * 4);
  float* Yb = S2;  // logits buffer (S2 dead by layer-3 ULAST)
  // precompute scratch aliased onto chunk arena (dead before chunk work starts)
  float* Gf = (float*)S1;                  // 16MB
  f16* Gh = (f16*)((char*)S1 + 4 * UU * 4);  // 8MB

  // ---- weight precompute ----
  wins<<<dim3((unsigned)(UU / 256)), 256, 0, stream>>>(Win, Winh, Winl);
  wsplit4<<<dim3(32, 32, 4), dim3(32, 8), 0, stream>>>(Wgt[0], Wgt[1], Wgt[2], Wgt[3],
                                                       Wh, Wl, WTh, WTl);
  {  // G = W^T W (all 4 layers, TRI)
    Ep e{};
    e.fa = Gf; e.ha = Gh; e.sAinv = 1.f;
    gk<OPX_G, 3><<<dim3(64, 4), 256, 0, stream>>>(WTh, WTl, WTh, WTl, UU, e);
  }
  {  // E2 = 20480*(c^2 G^2 - c G)
    Ep e{};
    e.ra = Gf; e.ha = E2; e.sAinv = 1.f;
    gk<OPX_E, 1><<<dim3(64, 4), 256, 0, stream>>>(Gh, Gh, Gh, Gh, UU, e);
  }
  {  // WpT = W^T + E@W^T  (A=E2, Bt=W split)
    Ep e{};
    e.ha = WpTh; e.la = WpTl;
    e.ra = Wgt[0]; e.rb = Wgt[1]; e.bias = Wgt[2]; e.bias2 = Wgt[3];
    e.sAinv = 1.f;
    gk<OPX_WPT, 3><<<dim3(64, 4), 256, 0, stream>>>(E2, E2, Wh, Wl, UU, e);
  }

  const float SIG[4] = {16.f, 2.f, 0.25f, 0.03125f};
  const int nch = 8192 / Mc;
  const dim3 gg((unsigned)(Mc / 128) * 8);
  const dim3 gg2((unsigned)(Mc / 128) * 16);

  for (int ch = 0; ch < nch; ++ch) {
    const size_t r0 = (size_t)ch * Mc;
    xsplit<<<dim3(Mc * 4), 256, 0, stream>>>(x + r0 * 784, Qh, Ql);
    {  // z = x@Win^T + b_in; r1(0)->P0, r2(0)->R2
      Ep e{};
      e.bias = bin; e.bias2 = bl[0];
      e.ha = P0h; e.la = P0l; e.hb = R2h; e.lb = R2l;
      e.sAinv = 1.f / 16.f; e.sOut = 16.f;
      gk<OPX_Z0, 3><<<gg, 256, 0, stream>>>(Qh, Ql, Winh, Winl, 0, e);
    }
    for (int l = 0; l < 4; l++) {
      const float sl = SIG[l], sli = 1.f / sl;
      const bool zf = (l == 0);
      {  // VNEW: v = (r2 + r2@E + 0.1*r1@Wp)/11 -> P2 ; p = v+s2 -> Q[CF..)
        Ep e{};
        e.a2 = R2h; e.b2 = E2 + l * UU;
        e.xh = R2h; e.xl = R2l; e.sX = sli;
        e.rb = zf ? nullptr : S2;
        e.ha = P2h; e.la = P2l;
        if (l < 3) { e.hb = Qh + CF; e.lb = Ql + CF; }
        e.sAinv = sli; e.sOut = sl;
        gk<OPX_VN, 4><<<gg, 256, 0, stream>>>(P0h, P0l, WpTh + l * UU, WpTl + l * UU, 0, e);
      }
      if (l < 3) {
        {  // U: q = r1 - 0.1*v@W^T + s1 -> Q[0..CF)
          Ep e{};
          e.xh = P0h; e.xl = P0l; e.sX = sli;
          e.rb = zf ? nullptr : S1;
          e.ha = Qh; e.la = Ql;
          e.sAinv = sli; e.sOut = sl;
          gk<OPX_U, 3><<<gg, 256, 0, stream>>>(P2h, P2l, Wh + l * UU, Wl + l * UU, 0, e);
        }
        {  // QP merged: rows<Mc: q@W -> r2',s2' ; rows>=Mc: p@W^T -> r1',s1'
          Ep e{};
          e.Mh = Mc;
          e.xh = Qh; e.xl = Ql; e.sX = sli;
          e.yh = P2h; e.yl = P2l; e.sY = sli;
          e.rb = zf ? nullptr : S2;
          e.ra = zf ? nullptr : S1;
          e.ha = R2h; e.la = R2l;      // r2' (scale SIG[l+1])
          e.fb = S2;                   // s2'
          e.fa = S1;                   // s1'
          e.hb = P0h; e.lb = P0l;      // r1'
          e.bias = bl[l + 1];
          e.b3h = Wh + l * UU; e.b3l = Wl + l * UU;
          e.sAinv = sli; e.sOut = SIG[l + 1];
          gk<OPX_QP, 3><<<gg2, 256, 0, stream>>>(Qh, Ql, WTh + l * UU, WTl + l * UU, 0, e);
        }
      } else {  // ULAST: logits = -(r1 - 0.1*v@W^T + s1) -> Yb
        Ep e{};
        e.xh = P0h; e.xl = P0l; e.sX = sli;
        e.rb = S1; e.fb = Yb; e.sAinv = sli;
        gk<OPX_UL, 3><<<gg, 256, 0, stream>>>(P2h, P2l, Wh + 3 * UU, Wl + 3 * UU, 0, e);
      }
    }
    out_softmax<<<dim3(Mc / 4), 256, 0, stream>>>(Yb, Wout, bout, out + r0 * 10);
  }
}

// Round 6
// 2019.484 us; speedup vs baseline: 1.7337x; 1.0141x over previous
//
#include <hip/hip_runtime.h>

typedef _Float16 f16;
typedef _Float16 f16x8 __attribute__((ext_vector_type(8)));
typedef _Float16 f16x4 __attribute__((ext_vector_type(4)));
typedef float f32x4 __attribute__((ext_vector_type(4)));

#define GLD(g, l) __builtin_amdgcn_global_load_lds( \
    (const __attribute__((address_space(1))) void*)(g), \
    (__attribute__((address_space(3))) void*)(l), 16, 0, 0)

enum { MZ0, MVN, MU, MUL, MQP, MG, ME, MWP };

struct Ep {
  const f16* A[4]; const f16* B[4];    // slice tables (primary / q-half)
  const f16* A2[4]; const f16* B2[4];  // QP p-half
  f16 *o0h, *o0l, *o1h, *o1l, *o2h, *o2l;
  float* of;
  const f16 *x0h, *x0l, *x1h, *x1l, *x2h, *x2l, *x3h, *x3l;
  const float* rf0;
  const float *w0, *w1, *w2, *w3;
  const float *bias, *bias2;
  float sAi, sSi, sPi, sO, sO2;
  int Mh, dos2;
  size_t zA, zB, zO;
};

__device__ __forceinline__ float rec2(const f16* h, const f16* l, size_t i) {
  return (float)h[i] + (float)l[i];
}
__device__ __forceinline__ void wp2(f16* h, f16* l, size_t i, float v) {
  const f16 hi = (f16)v;
  h[i] = hi;
  l[i] = (f16)(v - (float)hi);
}

// C = sum_s A[s] @ B[s]^T, each slice [M][1024]x[1024][1024]; uniform x32 product scale.
// 128x128 tiles, BK=32, slices grouped (<=3 staged per K-step, 16 MFMA each).
template <int MODE, int NSL>
__global__ __launch_bounds__(256, 2) void gk(Ep ep) {
  constexpr int G0 = (NSL <= 3) ? NSL : 2;
  __shared__ f16 LA[G0][4096] __attribute__((aligned(16)));
  __shared__ f16 LB[G0][4096] __attribute__((aligned(16)));
  const int tid = threadIdx.x;
  const int w = tid >> 6, lane = tid & 63;
  const unsigned nb = gridDim.x;
  unsigned bid = blockIdx.x;
  bid = (bid & 7) * (nb >> 3) + (bid >> 3);  // XCD-chunked (nb % 8 == 0)
  const int tn = (int)(bid & 7) * 128;
  const int tm = (int)(bid >> 3) * 128;
  const int ly = blockIdx.y;
  const size_t zoA = (size_t)ly * ep.zA;
  const size_t zoB = (size_t)ly * ep.zB;
  const size_t zoO = (size_t)ly * ep.zO;

  const bool half2 = (MODE == MQP) && (tm >= ep.Mh);
  const int tmr = half2 ? tm - ep.Mh : tm;
  const f16* const* Ap = half2 ? ep.A2 : ep.A;
  const f16* const* Bp = half2 ? ep.B2 : ep.B;

  const int srow = w * 16 + (lane >> 2);
  const int scol = (lane & 3) * 8;
  const int wr = w >> 1, wc = w & 1;
  const int fr = lane & 15;
  const int kb = (lane >> 4) * 8;
  const int ao = (wr * 64 + fr) * 32 + kb;
  const int bo = (wc * 64 + fr) * 32 + kb;

  f32x4 acc[4][4] = {};

  for (int g = 0; g < NSL; g += G0) {
    for (int kt = 0; kt < 1024; kt += 32) {
      __syncthreads();
#pragma unroll
      for (int s = 0; s < G0; ++s) {
        const f16* ga = Ap[g + s] + zoA + (size_t)(tmr + srow) * 1024 + kt + scol;
        const f16* gb = Bp[g + s] + zoB + (size_t)(tn + srow) * 1024 + kt + scol;
        GLD(ga, LA[s] + w * 512);
        GLD(ga + 65536, LA[s] + 2048 + w * 512);
        GLD(gb, LB[s] + w * 512);
        GLD(gb + 65536, LB[s] + 2048 + w * 512);
      }
      __syncthreads();
#pragma unroll
      for (int s = 0; s < G0; ++s) {
        f16x8 af[4], bf[4];
#pragma unroll
        for (int i = 0; i < 4; i++) af[i] = *(const f16x8*)(LA[s] + ao + i * 512);
#pragma unroll
        for (int i = 0; i < 4; i++) bf[i] = *(const f16x8*)(LB[s] + bo + i * 512);
#pragma unroll
        for (int mi = 0; mi < 4; mi++)
#pragma unroll
          for (int ni = 0; ni < 4; ni++)
            acc[mi][ni] = __builtin_amdgcn_mfma_f32_16x16x32_f16(af[mi], bf[ni], acc[mi][ni], 0, 0, 0);
      }
    }
  }

  // C/D layout: col = lane&15, row = (lane>>4)*4 + j
  const int er = wr * 64 + ((lane >> 4) << 2);
  const int ec = wc * 64 + fr;
#pragma unroll
  for (int mi = 0; mi < 4; mi++)
#pragma unroll
    for (int ni = 0; ni < 4; ni++)
#pragma unroll
      for (int j = 0; j < 4; j++) {
        const int r = tmr + er + mi * 16 + j;
        const int c = tn + ec + ni * 16;
        const size_t i = (size_t)r * 1024 + c;
        const float av = acc[mi][ni][j];
        if constexpr (MODE == MZ0) {
          const float z = av * ep.sAi + ep.bias[c];
          wp2(ep.o0h, ep.o0l, i, 0.1f * (z + 0.1f * ep.bias2[c]) * ep.sO);  // 0.1*r1*SIG
          wp2(ep.o1h, ep.o1l, i, 11.f * fmaxf(z, 0.f) * ep.sO);            // r2*SIG
          wp2(ep.o2h, ep.o2l, i, 0.f);                                     // s2 = 0
          ep.of[i] = 0.f;                                                  // s1 = 0
        } else if constexpr (MODE == MVN) {
          const float G = av * ep.sAi;                       // 0.1*r1@Wp + r2@E
          const float r2 = rec2(ep.x0h, ep.x0l, i) * ep.sSi;
          const float v = (r2 + G) * (1.f / 11.f);
          if (ep.dos2) {
            const float s2o = rec2(ep.x2h, ep.x2l, i) * ep.sPi;
            const float vo = rec2(ep.x1h, ep.x1l, i) * ep.sPi;
            const float qo = rec2(ep.x3h, ep.x3l, i) * ep.sPi;
            wp2(ep.o1h, ep.o1l, i, (-r2 - s2o - vo + 10.f * fmaxf(-qo, 0.f)) * ep.sO);
          }
          wp2(ep.o0h, ep.o0l, i, v * ep.sO);                 // after reading old v
        } else if constexpr (MODE == MU || MODE == MUL) {
          const float vW = av * ep.sAi;
          const float r1 = rec2(ep.x0h, ep.x0l, i) * ep.sSi * 10.f;
          const float q = r1 - 0.1f * vW + ep.rf0[i];
          if constexpr (MODE == MU)
            wp2(ep.o0h, ep.o0l, i, q * ep.sO);               // q in-place over r1
          else
            wp2(ep.o0h, ep.o0l, i, -q);                      // logits-u3, scale 1
        } else if constexpr (MODE == MQP) {
          if (!half2) {
            const float qW = av * ep.sAi;
            const float v = rec2(ep.x1h, ep.x1l, i) * ep.sSi;
            const float s2 = rec2(ep.x2h, ep.x2l, i) * ep.sSi;
            const float qq = rec2(ep.x0h, ep.x0l, i) * ep.sSi;
            wp2(ep.o0h, ep.o0l, i,
                (10.f * v + 9.f * s2 + 10.f * fmaxf(-qq, 0.f) - 0.1f * qW) * ep.sO2);  // r2'
          } else {
            const float pW = av * ep.sAi;
            const float s1 = ep.rf0[i];
            const float qq = rec2(ep.x0h, ep.x0l, i) * ep.sSi;
            ep.of[i] = -(qq - s1) - 0.1f * pW;                                          // s1'
            wp2(ep.o1h, ep.o1l, i, 0.1f * (0.1f * ep.bias2[c] - s1 + 0.1f * pW) * ep.sO2);  // 0.1*r1'
          }
        } else if constexpr (MODE == MG) {
          const float gv = av * (1.f / 1024.f);
          ep.of[zoO + i] = gv;
          ep.o0h[zoO + i] = (f16)gv;
        } else if constexpr (MODE == ME) {
          constexpr float C1 = 0.01f / 11.f;
          ep.o0h[zoO + i] = (f16)(32.f * (C1 * C1 * av - C1 * ep.rf0[zoO + i]));
        } else if constexpr (MODE == MWP) {
          const float* Wf = ly == 0 ? ep.w0 : ly == 1 ? ep.w1 : ly == 2 ? ep.w2 : ep.w3;
          const float s = 32.f * (Wf[(size_t)c * 1024 + r] + av * (1.f / 1024.f));  // WpT = W^T + E@W^T
          const f16 hi = (f16)s;
          ep.o0h[zoO + i] = hi;
          ep.o0l[zoO + i] = (f16)(s - (float)hi);
        }
      }
}

template <int MC>
__global__ void mcprobe() {}  // Mc diagnostic: name appears in the profile

// x: pad 784->1024, scale 16, split {h, raw residual}
__global__ __launch_bounds__(256) void xstage(const float* __restrict__ src,
                                              f16* __restrict__ h, f16* __restrict__ l) {
  const size_t i = (size_t)blockIdx.x * 256 + threadIdx.x;
  const int k = (int)(i & 1023);
  const size_t m = i >> 10;
  const float s = (k < 784) ? 16.f * src[m * 784 + k] : 0.f;
  const f16 hi = (f16)s;
  h[i] = hi;
  l[i] = (f16)(s - (float)hi);
}

// Win: pad 784->1024, x32 split
__global__ __launch_bounds__(256) void winstage(const float* __restrict__ src,
                                                f16* __restrict__ h, f16* __restrict__ l) {
  const size_t i = (size_t)blockIdx.x * 256 + threadIdx.x;
  const int k = (int)(i & 1023);
  const size_t m = i >> 10;
  const float s = (k < 784) ? 32.f * src[m * 784 + k] : 0.f;
  const f16 hi = (f16)s;
  h[i] = hi;
  l[i] = (f16)(s - (float)hi);
}

// 4 layer weights -> x32 split, direct + transposed
__global__ __launch_bounds__(256) void wstage(const float* __restrict__ W0, const float* __restrict__ W1,
                                              const float* __restrict__ W2, const float* __restrict__ W3,
                                              f16* __restrict__ Wh, f16* __restrict__ Wl,
                                              f16* __restrict__ WTh, f16* __restrict__ WTl) {
  __shared__ float t[32][33];
  const int lz = blockIdx.z;
  const float* W = lz == 0 ? W0 : lz == 1 ? W1 : lz == 2 ? W2 : W3;
  const size_t off = (size_t)lz * 1024 * 1024;
  const int c0 = blockIdx.x * 32, r0 = blockIdx.y * 32;
  const int tx = threadIdx.x, ty = threadIdx.y;
#pragma unroll
  for (int i = ty; i < 32; i += 8) {
    const float v = W[(size_t)(r0 + i) * 1024 + c0 + tx];
    t[i][tx] = v;
    const float s = 32.f * v;
    const f16 hi = (f16)s;
    Wh[off + (size_t)(r0 + i) * 1024 + c0 + tx] = hi;
    Wl[off + (size_t)(r0 + i) * 1024 + c0 + tx] = (f16)(s - (float)hi);
  }
  __syncthreads();
#pragma unroll
  for (int i = ty; i < 32; i += 8) {
    const float s = 32.f * t[tx][i];
    const f16 hi = (f16)s;
    WTh[off + (size_t)(c0 + i) * 1024 + r0 + tx] = hi;
    WTl[off + (size_t)(c0 + i) * 1024 + r0 + tx] = (f16)(s - (float)hi);
  }
}

// logits = softmax(rec(L) @ Wout^T + bout); one wave per row
__global__ __launch_bounds__(256) void out_softmax(const f16* __restrict__ Lh, const f16* __restrict__ Ll,
                                                   const float* __restrict__ Wout,
                                                   const float* __restrict__ bo,
                                                   float* __restrict__ out) {
  const int row = blockIdx.x * 4 + (threadIdx.x >> 6);
  const int lane = threadIdx.x & 63;
  const size_t rb = (size_t)row * 1024;
  float p[10];
#pragma unroll
  for (int t = 0; t < 10; t++) p[t] = 0.f;
#pragma unroll
  for (int j = 0; j < 4; j++) {
    const int kbase = (j * 64 + lane) * 4;
    const f16x4 hv = *(const f16x4*)(Lh + rb + kbase);
    const f16x4 lv = *(const f16x4*)(Ll + rb + kbase);
    float uv[4];
#pragma unroll
    for (int e = 0; e < 4; e++) uv[e] = (float)hv[e] + (float)lv[e];
#pragma unroll
    for (int t = 0; t < 10; t++) {
      const float4 wv = *(const float4*)(Wout + t * 1024 + kbase);
      p[t] += uv[0] * wv.x + uv[1] * wv.y + uv[2] * wv.z + uv[3] * wv.w;
    }
  }
#pragma unroll
  for (int off = 32; off; off >>= 1)
#pragma unroll
    for (int t = 0; t < 10; t++) p[t] += __shfl_down(p[t], off);
  if (lane == 0) {
    float lg[10], m = -1e30f, s = 0.f;
#pragma unroll
    for (int t = 0; t < 10; t++) { lg[t] = p[t] + bo[t]; m = fmaxf(m, lg[t]); }
#pragma unroll
    for (int t = 0; t < 10; t++) { lg[t] = expf(lg[t] - m); s += lg[t]; }
    const float inv = 1.f / s;
    float* o = out + (size_t)row * 10;
#pragma unroll
    for (int t = 0; t < 10; t++) o[t] = lg[t] * inv;
  }
}

extern "C" void kernel_launch(void* const* d_in, const int* in_sizes, int n_in,
                              void* d_out, int out_size, void* d_ws, size_t ws_size,
                              hipStream_t stream) {
  const float* x = (const float*)d_in[0];
  const float* Win = (const float*)d_in[1];
  const float* bin = (const float*)d_in[2];
  const float* Wgt[4] = {(const float*)d_in[3], (const float*)d_in[5],
                         (const float*)d_in[7], (const float*)d_in[9]};
  const float* bl[4] = {(const float*)d_in[4], (const float*)d_in[6],
                        (const float*)d_in[8], (const float*)d_in[10]};
  const float* Wout = (const float*)d_in[11];
  const float* bout = (const float*)d_in[12];
  float* out = (float*)d_out;

  char* p = (char*)d_ws;
  auto take = [&](size_t n) {
    void* q = (void*)p;
    p += (n + 255) & ~(size_t)255;
    return q;
  };
  const size_t UM = (size_t)1024 * 1024;

  // weights (~60MB)
  f16* Winh = (f16*)take(UM * 2);
  f16* Winl = (f16*)take(UM * 2);
  f16* Wh = (f16*)take(4 * UM * 2);
  f16* Wl = (f16*)take(4 * UM * 2);
  f16* WTh = (f16*)take(4 * UM * 2);
  f16* WTl = (f16*)take(4 * UM * 2);
  f16* WpTh = (f16*)take(4 * UM * 2);
  f16* WpTl = (f16*)take(4 * UM * 2);
  f16* E32 = (f16*)take(4 * UM * 2);
  const size_t fixedB = (size_t)(p - (char*)d_ws);

  int Mc = 8192;
  auto actB = [&](int m) {
    size_t a = (size_t)m * 1024 * 24;           // 10 f16 planes + 1 f32
    if (m < 4096) a += 24 * UM;                 // dedicated G scratch
    return a;
  };
  while (Mc > 1024 && fixedB + actB(Mc) + 65536 > ws_size) Mc >>= 1;
  if (fixedB + actB(Mc) + 65536 > ws_size) return;
  const size_t CF = (size_t)Mc * 1024;

  f16* P0h = (f16*)take(CF * 2); f16* P0l = (f16*)take(CF * 2);
  f16* Qh = (f16*)take(CF * 2);  f16* Ql = (f16*)take(CF * 2);
  f16* R2h = (f16*)take(CF * 2); f16* R2l = (f16*)take(CF * 2);
  f16* P2h = (f16*)take(CF * 2); f16* P2l = (f16*)take(CF * 2);
  f16* S2h = (f16*)take(CF * 2); f16* S2l = (f16*)take(CF * 2);
  float* S1 = (float*)take(CF * 4);
  float* Gf;
  f16* Gh;
  if (Mc >= 4096) {  // alias precompute scratch over act planes (dead then)
    Gf = (float*)P0h;  // 16MB over P0h+P0l
    Gh = (f16*)Qh;     // 8MB over Qh(+Ql)
  } else {
    Gf = (float*)take(4 * UM * 4);
    Gh = (f16*)take(4 * UM * 2);
  }

  switch (Mc) {  // diagnostic: chosen Mc shows up as kernel name in profile
    case 8192: mcprobe<8><<<1, 1, 0, stream>>>(); break;
    case 4096: mcprobe<4><<<1, 1, 0, stream>>>(); break;
    case 2048: mcprobe<2><<<1, 1, 0, stream>>>(); break;
    default:   mcprobe<1><<<1, 1, 0, stream>>>(); break;
  }

  // ---- weight precompute ----
  winstage<<<dim3((unsigned)(UM / 256)), 256, 0, stream>>>(Win, Winh, Winl);
  wstage<<<dim3(32, 32, 4), dim3(32, 8), 0, stream>>>(Wgt[0], Wgt[1], Wgt[2], Wgt[3],
                                                      Wh, Wl, WTh, WTl);
  {  // G = W^T W (TRI), batched over layers
    Ep e{};
    e.A[0] = WTh; e.A[1] = WTh; e.A[2] = WTl;
    e.B[0] = WTh; e.B[1] = WTl; e.B[2] = WTh;
    e.zA = UM; e.zB = UM; e.zO = UM;
    e.of = Gf; e.o0h = Gh;
    gk<MG, 3><<<dim3(64, 4), 256, 0, stream>>>(e);
  }
  {  // E32 = 32*(c^2 G^2 - c G)
    Ep e{};
    e.A[0] = Gh; e.B[0] = Gh; e.zA = UM; e.zB = UM; e.zO = UM;
    e.rf0 = Gf; e.o0h = E32;
    gk<ME, 1><<<dim3(64, 4), 256, 0, stream>>>(e);
  }
  {  // WpT = W^T + E @ W^T (x32 split)
    Ep e{};
    e.A[0] = E32; e.B[0] = Wh; e.zA = UM; e.zB = UM; e.zO = UM;
    e.w0 = Wgt[0]; e.w1 = Wgt[1]; e.w2 = Wgt[2]; e.w3 = Wgt[3];
    e.o0h = WpTh; e.o0l = WpTl;
    gk<MWP, 1><<<dim3(64, 4), 256, 0, stream>>>(e);
  }

  const float SIG[5] = {16.f, 2.f, 0.25f, 0.03125f, 1.f};
  const int nch = 8192 / Mc;
  const dim3 gg((unsigned)(Mc / 128) * 8);
  const dim3 gg2((unsigned)(Mc / 128) * 16);

  for (int ch = 0; ch < nch; ++ch) {
    const size_t r0 = (size_t)ch * Mc;
    xstage<<<dim3(Mc * 4), 256, 0, stream>>>(x + r0 * 784, Qh, Ql);
    {  // Z0: z = x@Win^T + b_in -> P0 (0.1*r1), R2, S2=0, S1=0
      Ep e{};
      e.A[0] = Qh; e.A[1] = Qh; e.A[2] = Ql;
      e.B[0] = Winh; e.B[1] = Winl; e.B[2] = Winh;
      e.bias = bin; e.bias2 = bl[0];
      e.o0h = P0h; e.o0l = P0l; e.o1h = R2h; e.o1l = R2l; e.o2h = S2h; e.o2l = S2l;
      e.of = S1; e.sAi = 1.f / 512.f; e.sO = 16.f;
      e.Mh = 1 << 30;
      gk<MZ0, 3><<<gg, 256, 0, stream>>>(e);
    }
    for (int l = 0; l < 4; l++) {
      const size_t lz = (size_t)l * UM;
      const float sl = SIG[l];
      f16 *bCh = (l & 1) ? Qh : P0h, *bCl = (l & 1) ? Ql : P0l;   // r1_l -> q_l
      f16 *bAh = (l & 1) ? P0h : Qh, *bAl = (l & 1) ? P0l : Ql;   // q_{l-1} / r1_{l+1}
      {  // VNEW: v = (r2 + 0.1 r1@Wp + r2@E)/11 -> P2 ; s2-update (l>=1) -> S2
        Ep e{};
        e.A[0] = bCh; e.A[1] = bCh; e.A[2] = bCl; e.A[3] = R2h;
        e.B[0] = WpTh + lz; e.B[1] = WpTl + lz; e.B[2] = WpTh + lz; e.B[3] = E32 + lz;
        e.x0h = R2h; e.x0l = R2l;
        e.x1h = P2h; e.x1l = P2l;
        e.x2h = S2h; e.x2l = S2l;
        e.x3h = bAh; e.x3l = bAl;
        e.o0h = P2h; e.o0l = P2l; e.o1h = S2h; e.o1l = S2l;
        e.sAi = 1.f / (32.f * sl); e.sSi = 1.f / sl;
        e.sPi = l ? 1.f / SIG[l - 1] : 0.f; e.sO = sl;
        e.dos2 = l ? 1 : 0; e.Mh = 1 << 30;
        gk<MVN, 4><<<gg, 256, 0, stream>>>(e);
      }
      if (l < 3) {
        {  // U: q = r1 - 0.1 v@W^T + s1 -> in-place over r1
          Ep e{};
          e.A[0] = P2h; e.A[1] = P2h; e.A[2] = P2l;
          e.B[0] = Wh + lz; e.B[1] = Wl + lz; e.B[2] = Wh + lz;
          e.x0h = bCh; e.x0l = bCl; e.rf0 = S1;
          e.o0h = bCh; e.o0l = bCl;
          e.sAi = 1.f / (32.f * sl); e.sSi = 1.f / sl; e.sO = sl;
          e.Mh = 1 << 30;
          gk<MU, 3><<<gg, 256, 0, stream>>>(e);
        }
        {  // QP merged: q-half q@W -> r2' ; p-half (v+s2)@W^T -> s1', r1'
          Ep e{};
          e.A[0] = bCh; e.A[1] = bCh; e.A[2] = bCl;
          e.B[0] = WTh + lz; e.B[1] = WTl + lz; e.B[2] = WTh + lz;
          e.A2[0] = P2h; e.A2[1] = P2l; e.A2[2] = S2h;
          e.B2[0] = Wh + lz; e.B2[1] = Wh + lz; e.B2[2] = Wh + lz;
          e.x0h = bCh; e.x0l = bCl;
          e.x1h = P2h; e.x1l = P2l;
          e.x2h = S2h; e.x2l = S2l;
          e.rf0 = S1; e.of = S1;
          e.o0h = R2h; e.o0l = R2l;        // r2'
          e.o1h = bAh; e.o1l = bAl;        // 0.1*r1'
          e.bias2 = bl[l + 1];
          e.sAi = 1.f / (32.f * sl); e.sSi = 1.f / sl; e.sO2 = SIG[l + 1];
          e.Mh = Mc;
          gk<MQP, 3><<<gg2, 256, 0, stream>>>(e);
        }
      } else {  // UL: logits-u3 = -(r1 - 0.1 v@W^T + s1) -> R2 pair (scale 1)
        Ep e{};
        e.A[0] = P2h; e.A[1] = P2h; e.A[2] = P2l;
        e.B[0] = Wh + lz; e.B[1] = Wl + lz; e.B[2] = Wh + lz;
        e.x0h = bCh; e.x0l = bCl; e.rf0 = S1;
        e.o0h = R2h; e.o0l = R2l;
        e.sAi = 1.f / (32.f * sl); e.sSi = 1.f / sl; e.sO = 1.f;
        e.Mh = 1 << 30;
        gk<MUL, 3><<<gg, 256, 0, stream>>>(e);
      }
    }
    out_softmax<<<dim3(Mc / 4), 256, 0, stream>>>(R2h, R2l, Wout, bout, out + r0 * 10);
  }
}

// Round 7
// 1784.781 us; speedup vs baseline: 1.9617x; 1.1315x over previous
//
#include <hip/hip_runtime.h>

typedef _Float16 f16;
typedef _Float16 f16x8 __attribute__((ext_vector_type(8)));
typedef _Float16 f16x4 __attribute__((ext_vector_type(4)));
typedef float f32x4 __attribute__((ext_vector_type(4)));

#define GLD(g, l) __builtin_amdgcn_global_load_lds( \
    (const __attribute__((address_space(1))) void*)(g), \
    (__attribute__((address_space(3))) void*)(l), 16, 0, 0)

enum { MZ0, MVN, MU, MUL, MQP, MG, ME, MWP };

struct Ep {
  const f16 *Ah, *Al, *Bh, *Bl, *A2, *B2;  // unique planes (primary / q-half)
  const f16 *Ch, *Cl, *C2, *Dh;            // QP p-half planes
  f16 *o0h, *o0l, *o1h, *o1l, *o2h, *o2l;
  float* of;
  const f16 *x0h, *x0l, *x1h, *x1l, *x2h, *x2l, *x3h, *x3l;
  const float* rf0;
  const float *w0, *w1, *w2, *w3;
  const float *bias, *bias2;
  float sAi, sSi, sPi, sO, sO2;
  int Mh, dos2;
  size_t zA, zB, zO;
};

__device__ __forceinline__ float rec2(const f16* h, const f16* l, size_t i) {
  return (float)h[i] + (float)l[i];
}
__device__ __forceinline__ void wp2(f16* h, f16* l, size_t i, float v) {
  const f16 hi = (f16)v;
  h[i] = hi;
  l[i] = (f16)(v - (float)hi);
}

// C = sum_passes A_p @ B_p^T over staged planes; 64x128 tiles, BK=32, 4 waves (2x2).
// NSL=1: {Ah}x{Bh}. NSL=3: TRI {hh,hl,lh}. NSL=4: TRI + A2@B2 (VNEW).
// NSL=5: QP dual-half (q: TRI on Ah/Al/Bh/Bl ; p: {Ch,Cl,C2}@Dh).
// All products at uniform x32*SIG scale -> single f32 accumulator bank.
template <int MODE, int NSL>
__global__ __launch_bounds__(256, 4) void gk(Ep ep) {
  constexpr bool HL = NSL >= 3;
  constexpr bool HA2 = NSL >= 4;
  constexpr bool HB2 = NSL == 4;
  __shared__ f16 SAh[2048] __attribute__((aligned(16)));
  __shared__ f16 SBh[4096] __attribute__((aligned(16)));
  __shared__ f16 SAl[HL ? 2048 : 16] __attribute__((aligned(16)));
  __shared__ f16 SBl[HL ? 4096 : 16] __attribute__((aligned(16)));
  __shared__ f16 SA2[HA2 ? 2048 : 16] __attribute__((aligned(16)));
  __shared__ f16 SB2[HB2 ? 4096 : 16] __attribute__((aligned(16)));
  const int tid = threadIdx.x;
  const int w = tid >> 6, lane = tid & 63;
  const unsigned nb = gridDim.x;
  unsigned bid = blockIdx.x;
  bid = (bid & 7) * (nb >> 3) + (bid >> 3);  // XCD-chunked (nb % 8 == 0)
  const int tn = (int)(bid & 7) * 128;
  const int tm = (int)(bid >> 3) * 64;
  const int ly = blockIdx.y;
  const size_t zoA = (size_t)ly * ep.zA;
  const size_t zoB = (size_t)ly * ep.zB;
  const size_t zoO = (size_t)ly * ep.zO;

  const bool half2 = (MODE == MQP) && (tm >= ep.Mh);
  const int tmr = half2 ? tm - ep.Mh : tm;

  // per-lane global offsets (A: 64 rows, 1 GLD; B: 128 rows, 2 GLDs)
  const int arow = w * 16 + (lane >> 2);
  const int acol = (lane & 3) * 8;
  const size_t aoff = zoA + (size_t)(tmr + arow) * 1024 + acol;
  const size_t boff = zoB + (size_t)(tn + arow) * 1024 + acol;

  const f16* pAh = half2 ? ep.Ch : ep.Ah;
  const f16* pAl = half2 ? ep.Cl : ep.Al;
  const f16* pBh = half2 ? ep.Dh : ep.Bh;
  const f16* pBl = ep.Bl;
  const f16* pA2 = (MODE == MQP) ? ep.C2 : ep.A2;

  const int wr = w >> 1, wc = w & 1;
  const int fr = lane & 15;
  const int kb = (lane >> 4) * 8;
  const int ao = (wr * 32 + fr) * 32 + kb;
  const int bo = (wc * 64 + fr) * 32 + kb;

  f32x4 acc[2][4] = {};

  for (int kt = 0; kt < 1024; kt += 32) {
    __syncthreads();
    GLD(pAh + aoff + kt, SAh + w * 512);
    GLD(pBh + boff + kt, SBh + w * 512);
    GLD(pBh + boff + 65536 + kt, SBh + 2048 + w * 512);
    if constexpr (HL) {
      GLD(pAl + aoff + kt, SAl + w * 512);
      if (MODE != MQP || !half2) {
        GLD(pBl + boff + kt, SBl + w * 512);
        GLD(pBl + boff + 65536 + kt, SBl + 2048 + w * 512);
      }
    }
    if constexpr (NSL == 5) {
      if (half2) GLD(pA2 + aoff + kt, SA2 + w * 512);
    }
    if constexpr (HB2) {
      GLD(pA2 + aoff + kt, SA2 + w * 512);
      GLD(ep.B2 + boff + kt, SB2 + w * 512);
      GLD(ep.B2 + boff + 65536 + kt, SB2 + 2048 + w * 512);
    }
    __syncthreads();

    auto pass = [&](const f16* SA, const f16* SB) {
      f16x8 af[2], bf[4];
#pragma unroll
      for (int i = 0; i < 2; i++) af[i] = *(const f16x8*)(SA + ao + i * 512);
#pragma unroll
      for (int i = 0; i < 4; i++) bf[i] = *(const f16x8*)(SB + bo + i * 512);
#pragma unroll
      for (int mi = 0; mi < 2; mi++)
#pragma unroll
        for (int ni = 0; ni < 4; ni++)
          acc[mi][ni] = __builtin_amdgcn_mfma_f32_16x16x32_f16(af[mi], bf[ni], acc[mi][ni], 0, 0, 0);
    };

    if constexpr (NSL == 5) {
      if (half2) {
        pass(SAh, SBh); pass(SAl, SBh); pass(SA2, SBh);
      } else {
        pass(SAh, SBh); pass(SAh, SBl); pass(SAl, SBh);
      }
    } else {
      pass(SAh, SBh);
      if constexpr (HL) { pass(SAh, SBl); pass(SAl, SBh); }
      if constexpr (HB2) { pass(SA2, SB2); }
    }
  }

  // C/D layout: col = lane&15, row = (lane>>4)*4 + j
  const int er = wr * 32 + ((lane >> 4) << 2);
  const int ec = wc * 64 + fr;
#pragma unroll
  for (int mi = 0; mi < 2; mi++)
#pragma unroll
    for (int ni = 0; ni < 4; ni++)
#pragma unroll
      for (int j = 0; j < 4; j++) {
        const int r = tmr + er + mi * 16 + j;
        const int c = tn + ec + ni * 16;
        const size_t i = (size_t)r * 1024 + c;
        const float av = acc[mi][ni][j];
        if constexpr (MODE == MZ0) {
          const float z = av * ep.sAi + ep.bias[c];
          wp2(ep.o0h, ep.o0l, i, 0.1f * (z + 0.1f * ep.bias2[c]) * ep.sO);  // 0.1*r1*SIG
          wp2(ep.o1h, ep.o1l, i, 11.f * fmaxf(z, 0.f) * ep.sO);            // r2*SIG
          wp2(ep.o2h, ep.o2l, i, 0.f);                                     // s2 = 0
          ep.of[i] = 0.f;                                                  // s1 = 0
        } else if constexpr (MODE == MVN) {
          const float G = av * ep.sAi;                  // 0.1*r1@Wp + r2@E
          const float r2 = rec2(ep.x0h, ep.x0l, i) * ep.sSi;
          const float v = (r2 + G) * (1.f / 11.f);
          if (ep.dos2) {
            const float s2o = rec2(ep.x2h, ep.x2l, i) * ep.sPi;
            const float vo = rec2(ep.x1h, ep.x1l, i) * ep.sPi;
            const float qo = rec2(ep.x3h, ep.x3l, i) * ep.sPi;
            wp2(ep.o1h, ep.o1l, i, (-r2 - s2o - vo + 10.f * fmaxf(-qo, 0.f)) * ep.sO);  // s2(l)
          }
          wp2(ep.o0h, ep.o0l, i, v * ep.sO);            // v (after reading old v)
        } else if constexpr (MODE == MU || MODE == MUL) {
          const float vW = av * ep.sAi;
          const float r1 = rec2(ep.x0h, ep.x0l, i) * ep.sSi * 10.f;
          const float q = r1 - 0.1f * vW + ep.rf0[i];
          if constexpr (MODE == MU)
            wp2(ep.o0h, ep.o0l, i, q * ep.sO);          // q in-place over r1
          else
            wp2(ep.o0h, ep.o0l, i, -q);                 // logits-u3 (scale 1)
        } else if constexpr (MODE == MQP) {
          if (!half2) {
            const float qW = av * ep.sAi;
            const float v = rec2(ep.x1h, ep.x1l, i) * ep.sSi;
            const float s2 = rec2(ep.x2h, ep.x2l, i) * ep.sSi;
            const float qq = rec2(ep.x0h, ep.x0l, i) * ep.sSi;
            wp2(ep.o0h, ep.o0l, i,
                (10.f * v + 9.f * s2 + 10.f * fmaxf(-qq, 0.f) - 0.1f * qW) * ep.sO2);  // r2'
          } else {
            const float pW = av * ep.sAi;
            const float s1 = ep.rf0[i];
            const float qq = rec2(ep.x0h, ep.x0l, i) * ep.sSi;
            ep.of[i] = -(qq - s1) - 0.1f * pW;                                          // s1'
            wp2(ep.o1h, ep.o1l, i, 0.1f * (0.1f * ep.bias2[c] - s1 + 0.1f * pW) * ep.sO2);  // 0.1*r1'
          }
        } else if constexpr (MODE == MG) {
          const float gv = av * (1.f / 1024.f);
          ep.of[zoO + i] = gv;
          ep.o0h[zoO + i] = (f16)gv;
        } else if constexpr (MODE == ME) {
          constexpr float C1 = 0.01f / 11.f;
          ep.o0h[zoO + i] = (f16)(32.f * (C1 * C1 * av - C1 * ep.rf0[zoO + i]));
        } else if constexpr (MODE == MWP) {
          const float* Wf = ly == 0 ? ep.w0 : ly == 1 ? ep.w1 : ly == 2 ? ep.w2 : ep.w3;
          const float s = 32.f * (Wf[(size_t)c * 1024 + r] + av * (1.f / 1024.f));  // WpT
          const f16 hi = (f16)s;
          ep.o0h[zoO + i] = hi;
          ep.o0l[zoO + i] = (f16)(s - (float)hi);
        }
      }
}

template <int MC>
__global__ void mcprobe() {}  // Mc diagnostic

// x: pad 784->1024, x16, split {h, raw residual}
__global__ __launch_bounds__(256) void xstage(const float* __restrict__ src,
                                              f16* __restrict__ h, f16* __restrict__ l) {
  const size_t i = (size_t)blockIdx.x * 256 + threadIdx.x;
  const int k = (int)(i & 1023);
  const size_t m = i >> 10;
  const float s = (k < 784) ? 16.f * src[m * 784 + k] : 0.f;
  const f16 hi = (f16)s;
  h[i] = hi;
  l[i] = (f16)(s - (float)hi);
}

// Win: pad 784->1024, x32 split
__global__ __launch_bounds__(256) void winstage(const float* __restrict__ src,
                                                f16* __restrict__ h, f16* __restrict__ l) {
  const size_t i = (size_t)blockIdx.x * 256 + threadIdx.x;
  const int k = (int)(i & 1023);
  const size_t m = i >> 10;
  const float s = (k < 784) ? 32.f * src[m * 784 + k] : 0.f;
  const f16 hi = (f16)s;
  h[i] = hi;
  l[i] = (f16)(s - (float)hi);
}

// 4 layer weights -> x32 split, direct + transposed
__global__ __launch_bounds__(256) void wstage(const float* __restrict__ W0, const float* __restrict__ W1,
                                              const float* __restrict__ W2, const float* __restrict__ W3,
                                              f16* __restrict__ Wh, f16* __restrict__ Wl,
                                              f16* __restrict__ WTh, f16* __restrict__ WTl) {
  __shared__ float t[32][33];
  const int lz = blockIdx.z;
  const float* W = lz == 0 ? W0 : lz == 1 ? W1 : lz == 2 ? W2 : W3;
  const size_t off = (size_t)lz * 1024 * 1024;
  const int c0 = blockIdx.x * 32, r0 = blockIdx.y * 32;
  const int tx = threadIdx.x, ty = threadIdx.y;
#pragma unroll
  for (int i = ty; i < 32; i += 8) {
    const float v = W[(size_t)(r0 + i) * 1024 + c0 + tx];
    t[i][tx] = v;
    const float s = 32.f * v;
    const f16 hi = (f16)s;
    Wh[off + (size_t)(r0 + i) * 1024 + c0 + tx] = hi;
    Wl[off + (size_t)(r0 + i) * 1024 + c0 + tx] = (f16)(s - (float)hi);
  }
  __syncthreads();
#pragma unroll
  for (int i = ty; i < 32; i += 8) {
    const float s = 32.f * t[tx][i];
    const f16 hi = (f16)s;
    WTh[off + (size_t)(c0 + i) * 1024 + r0 + tx] = hi;
    WTl[off + (size_t)(c0 + i) * 1024 + r0 + tx] = (f16)(s - (float)hi);
  }
}

// logits = softmax(rec(L) @ Wout^T + bout); one wave per row
__global__ __launch_bounds__(256) void out_softmax(const f16* __restrict__ Lh, const f16* __restrict__ Ll,
                                                   const float* __restrict__ Wout,
                                                   const float* __restrict__ bo,
                                                   float* __restrict__ out) {
  const int row = blockIdx.x * 4 + (threadIdx.x >> 6);
  const int lane = threadIdx.x & 63;
  const size_t rb = (size_t)row * 1024;
  float p[10];
#pragma unroll
  for (int t = 0; t < 10; t++) p[t] = 0.f;
#pragma unroll
  for (int j = 0; j < 4; j++) {
    const int kbase = (j * 64 + lane) * 4;
    const f16x4 hv = *(const f16x4*)(Lh + rb + kbase);
    const f16x4 lv = *(const f16x4*)(Ll + rb + kbase);
    float uv[4];
#pragma unroll
    for (int e = 0; e < 4; e++) uv[e] = (float)hv[e] + (float)lv[e];
#pragma unroll
    for (int t = 0; t < 10; t++) {
      const float4 wv = *(const float4*)(Wout + t * 1024 + kbase);
      p[t] += uv[0] * wv.x + uv[1] * wv.y + uv[2] * wv.z + uv[3] * wv.w;
    }
  }
#pragma unroll
  for (int off = 32; off; off >>= 1)
#pragma unroll
    for (int t = 0; t < 10; t++) p[t] += __shfl_down(p[t], off);
  if (lane == 0) {
    float lg[10], m = -1e30f, s = 0.f;
#pragma unroll
    for (int t = 0; t < 10; t++) { lg[t] = p[t] + bo[t]; m = fmaxf(m, lg[t]); }
#pragma unroll
    for (int t = 0; t < 10; t++) { lg[t] = expf(lg[t] - m); s += lg[t]; }
    const float inv = 1.f / s;
    float* o = out + (size_t)row * 10;
#pragma unroll
    for (int t = 0; t < 10; t++) o[t] = lg[t] * inv;
  }
}

extern "C" void kernel_launch(void* const* d_in, const int* in_sizes, int n_in,
                              void* d_out, int out_size, void* d_ws, size_t ws_size,
                              hipStream_t stream) {
  const float* x = (const float*)d_in[0];
  const float* Win = (const float*)d_in[1];
  const float* bin = (const float*)d_in[2];
  const float* Wgt[4] = {(const float*)d_in[3], (const float*)d_in[5],
                         (const float*)d_in[7], (const float*)d_in[9]};
  const float* bl[4] = {(const float*)d_in[4], (const float*)d_in[6],
                        (const float*)d_in[8], (const float*)d_in[10]};
  const float* Wout = (const float*)d_in[11];
  const float* bout = (const float*)d_in[12];
  float* out = (float*)d_out;

  char* p = (char*)d_ws;
  auto take = [&](size_t n) {
    void* q = (void*)p;
    p += (n + 255) & ~(size_t)255;
    return q;
  };
  const size_t UM = (size_t)1024 * 1024;

  // weights (~60MB)
  f16* Winh = (f16*)take(UM * 2);
  f16* Winl = (f16*)take(UM * 2);
  f16* Wh = (f16*)take(4 * UM * 2);
  f16* Wl = (f16*)take(4 * UM * 2);
  f16* WTh = (f16*)take(4 * UM * 2);
  f16* WTl = (f16*)take(4 * UM * 2);
  f16* WpTh = (f16*)take(4 * UM * 2);
  f16* WpTl = (f16*)take(4 * UM * 2);
  f16* E32 = (f16*)take(4 * UM * 2);
  const size_t fixedB = (size_t)(p - (char*)d_ws);

  int Mc = 8192;
  auto actB = [&](int m) {
    size_t a = (size_t)m * 1024 * 24;  // 10 f16 planes + 1 f32
    if (m < 4096) a += 24 * UM;        // dedicated G scratch
    return a;
  };
  while (Mc > 1024 && fixedB + actB(Mc) + 65536 > ws_size) Mc >>= 1;
  if (fixedB + actB(Mc) + 65536 > ws_size) return;
  const size_t CF = (size_t)Mc * 1024;

  f16* P0h = (f16*)take(CF * 2); f16* P0l = (f16*)take(CF * 2);
  f16* Qh = (f16*)take(CF * 2);  f16* Ql = (f16*)take(CF * 2);
  f16* R2h = (f16*)take(CF * 2); f16* R2l = (f16*)take(CF * 2);
  f16* P2h = (f16*)take(CF * 2); f16* P2l = (f16*)take(CF * 2);
  f16* S2h = (f16*)take(CF * 2); f16* S2l = (f16*)take(CF * 2);
  float* S1 = (float*)take(CF * 4);
  float* Gf;
  f16* Gh;
  if (Mc >= 4096) {    // alias precompute scratch over act planes (dead then)
    Gf = (float*)P0h;  // 16MB over P0h+P0l
    Gh = (f16*)Qh;     // 8MB over Qh
  } else {
    Gf = (float*)take(4 * UM * 4);
    Gh = (f16*)take(4 * UM * 2);
  }

  switch (Mc) {
    case 8192: mcprobe<8><<<1, 1, 0, stream>>>(); break;
    case 4096: mcprobe<4><<<1, 1, 0, stream>>>(); break;
    case 2048: mcprobe<2><<<1, 1, 0, stream>>>(); break;
    default:   mcprobe<1><<<1, 1, 0, stream>>>(); break;
  }

  // ---- weight precompute (all batched over 4 layers, 64-row tiles) ----
  winstage<<<dim3((unsigned)(UM / 256)), 256, 0, stream>>>(Win, Winh, Winl);
  wstage<<<dim3(32, 32, 4), dim3(32, 8), 0, stream>>>(Wgt[0], Wgt[1], Wgt[2], Wgt[3],
                                                      Wh, Wl, WTh, WTl);
  {  // G = W^T W (TRI)
    Ep e{};
    e.Ah = WTh; e.Al = WTl; e.Bh = WTh; e.Bl = WTl;
    e.zA = UM; e.zB = UM; e.zO = UM;
    e.of = Gf; e.o0h = Gh;
    gk<MG, 3><<<dim3(128, 4), 256, 0, stream>>>(e);
  }
  {  // E32 = 32*(c^2 G^2 - c G)
    Ep e{};
    e.Ah = Gh; e.Bh = Gh; e.zA = UM; e.zB = UM; e.zO = UM;
    e.rf0 = Gf; e.o0h = E32;
    gk<ME, 1><<<dim3(128, 4), 256, 0, stream>>>(e);
  }
  {  // WpT = W^T + E @ W^T (x32 split)
    Ep e{};
    e.Ah = E32; e.Bh = Wh; e.zA = UM; e.zB = UM; e.zO = UM;
    e.w0 = Wgt[0]; e.w1 = Wgt[1]; e.w2 = Wgt[2]; e.w3 = Wgt[3];
    e.o0h = WpTh; e.o0l = WpTl;
    gk<MWP, 1><<<dim3(128, 4), 256, 0, stream>>>(e);
  }

  const float SIG[5] = {16.f, 2.f, 0.25f, 0.03125f, 1.f};
  const int nch = 8192 / Mc;
  const dim3 gg((unsigned)(Mc / 64) * 8);
  const dim3 gg2((unsigned)(Mc / 64) * 16);

  for (int ch = 0; ch < nch; ++ch) {
    const size_t r0 = (size_t)ch * Mc;
    xstage<<<dim3(Mc * 4), 256, 0, stream>>>(x + r0 * 784, Qh, Ql);
    {  // Z0: z = x@Win^T + b_in -> P0 (0.1*r1), R2, S2=0, S1=0
      Ep e{};
      e.Ah = Qh; e.Al = Ql; e.Bh = Winh; e.Bl = Winl;
      e.bias = bin; e.bias2 = bl[0];
      e.o0h = P0h; e.o0l = P0l; e.o1h = R2h; e.o1l = R2l; e.o2h = S2h; e.o2l = S2l;
      e.of = S1; e.sAi = 1.f / 512.f; e.sO = 16.f;
      e.Mh = 1 << 30;
      gk<MZ0, 3><<<gg, 256, 0, stream>>>(e);
    }
    for (int l = 0; l < 4; l++) {
      const size_t lz = (size_t)l * UM;
      const float sl = SIG[l];
      f16 *bCh = (l & 1) ? Qh : P0h, *bCl = (l & 1) ? Ql : P0l;  // r1_l -> q_l
      f16 *bAh = (l & 1) ? P0h : Qh, *bAl = (l & 1) ? P0l : Ql;  // q_{l-1} / r1_{l+1}
      {  // VNEW: v = (r2 + 0.1 r1@Wp + r2@E)/11 -> P2 ; s2(l) -> S2 (l>=1)
        Ep e{};
        e.Ah = bCh; e.Al = bCl; e.Bh = WpTh + lz; e.Bl = WpTl + lz;
        e.A2 = R2h; e.B2 = E32 + lz;
        e.x0h = R2h; e.x0l = R2l;
        e.x1h = P2h; e.x1l = P2l;
        e.x2h = S2h; e.x2l = S2l;
        e.x3h = bAh; e.x3l = bAl;
        e.o0h = P2h; e.o0l = P2l; e.o1h = S2h; e.o1l = S2l;
        e.sAi = 1.f / (32.f * sl); e.sSi = 1.f / sl;
        e.sPi = l ? 1.f / SIG[l - 1] : 0.f; e.sO = sl;
        e.dos2 = l ? 1 : 0; e.Mh = 1 << 30;
        gk<MVN, 4><<<gg, 256, 0, stream>>>(e);
      }
      if (l < 3) {
        {  // U: q = 10*r1 - 0.1 v@W^T + s1 -> in-place over r1
          Ep e{};
          e.Ah = P2h; e.Al = P2l; e.Bh = Wh + lz; e.Bl = Wl + lz;
          e.x0h = bCh; e.x0l = bCl; e.rf0 = S1;
          e.o0h = bCh; e.o0l = bCl;
          e.sAi = 1.f / (32.f * sl); e.sSi = 1.f / sl; e.sO = sl;
          e.Mh = 1 << 30;
          gk<MU, 3><<<gg, 256, 0, stream>>>(e);
        }
        {  // QP: q-half q@W -> r2' ; p-half (v+s2h)@W^T -> s1', r1'
          Ep e{};
          e.Ah = bCh; e.Al = bCl; e.Bh = WTh + lz; e.Bl = WTl + lz;
          e.Ch = P2h; e.Cl = P2l; e.C2 = S2h; e.Dh = Wh + lz;
          e.x0h = bCh; e.x0l = bCl;
          e.x1h = P2h; e.x1l = P2l;
          e.x2h = S2h; e.x2l = S2l;
          e.rf0 = S1; e.of = S1;
          e.o0h = R2h; e.o0l = R2l;    // r2'
          e.o1h = bAh; e.o1l = bAl;    // 0.1*r1'
          e.bias2 = bl[l + 1];
          e.sAi = 1.f / (32.f * sl); e.sSi = 1.f / sl; e.sO2 = SIG[l + 1];
          e.Mh = Mc;
          gk<MQP, 5><<<gg2, 256, 0, stream>>>(e);
        }
      } else {  // UL: logits = -(10*r1 - 0.1 v@W^T + s1) -> R2 pair (scale 1)
        Ep e{};
        e.Ah = P2h; e.Al = P2l; e.Bh = Wh + lz; e.Bl = Wl + lz;
        e.x0h = bCh; e.x0l = bCl; e.rf0 = S1;
        e.o0h = R2h; e.o0l = R2l;
        e.sAi = 1.f / (32.f * sl); e.sSi = 1.f / sl; e.sO = 1.f;
        e.Mh = 1 << 30;
        gk<MUL, 3><<<gg, 256, 0, stream>>>(e);
      }
    }
    out_softmax<<<dim3(Mc / 4), 256, 0, stream>>>(R2h, R2l, Wout, bout, out + r0 * 10);
  }
}

// Round 8
// 1775.578 us; speedup vs baseline: 1.9718x; 1.0052x over previous
//
#include <hip/hip_runtime.h>

typedef _Float16 f16;
typedef _Float16 f16x8 __attribute__((ext_vector_type(8)));
typedef _Float16 f16x4 __attribute__((ext_vector_type(4)));
typedef float f32x4 __attribute__((ext_vector_type(4)));

#define GLD(g, l) __builtin_amdgcn_global_load_lds( \
    (const __attribute__((address_space(1))) void*)(g), \
    (__attribute__((address_space(3))) void*)(l), 16, 0, 0)

enum { MZ0, MVN, MU, MUL, MQP, MG, ME, MWP };

struct Ep {
  const f16 *Ah, *Al, *Bh, *Bl, *A2, *B2;  // unique planes (primary / q-half)
  const f16 *Ch, *Cl, *C2, *Dh;            // QP p-half planes
  f16 *o0h, *o0l, *o1h, *o1l, *o2h, *o2l;
  float* of;
  const f16 *x0h, *x0l, *x1h, *x1l, *x2h, *x2l, *x3h, *x3l;
  const float* rf0;
  const float *w0, *w1, *w2, *w3;
  const float *bias, *bias2;
  float sAi, sSi, sPi, sO, sO2;
  int Mh, dos2;
  size_t zA, zB, zO;
};

__device__ __forceinline__ float rec2(const f16* h, const f16* l, size_t i) {
  return (float)h[i] + (float)l[i];
}
__device__ __forceinline__ void wp2(f16* h, f16* l, size_t i, float v) {
  const f16 hi = (f16)v;
  h[i] = hi;
  l[i] = (f16)(v - (float)hi);
}

// C = sum_passes A_p @ B_p^T; 128x128 tiles, BK=32, 4 waves (2x2).
// Rotated K-loop: frags->regs, barrier, issue next-step GLDs, MFMA (loads fly under MFMA).
// NSL=1:{hh}. NSL=3: TRI {hh,hl,lh}. NSL=4: TRI + A2@B2. NSL=5: QP dual-half.
// Natural 2D grid: tn=bx*128 (consecutive blocks stripe XCDs -> B L2-resident per XCD).
template <int MODE, int NSL>
__global__ __launch_bounds__(256, 2) void gk(Ep ep) {
  constexpr int NA = (NSL == 1) ? 1 : (NSL == 3) ? 2 : 3;
  constexpr int NB = (NSL == 1) ? 1 : (NSL == 3) ? 2 : (NSL == 4) ? 3 : 2;
  __shared__ f16 SA[NA][4096] __attribute__((aligned(16)));
  __shared__ f16 SB[NB][4096] __attribute__((aligned(16)));
  const int tid = threadIdx.x;
  const int w = tid >> 6, lane = tid & 63;
  const int tn = blockIdx.x * 128;
  const int tm = blockIdx.y * 128;
  const int ly = blockIdx.z;
  const size_t zoA = (size_t)ly * ep.zA;
  const size_t zoB = (size_t)ly * ep.zB;
  const size_t zoO = (size_t)ly * ep.zO;

  const bool half2 = (MODE == MQP) && (tm >= ep.Mh);
  const int tmr = half2 ? tm - ep.Mh : tm;

  const f16 *pA0 = ep.Ah, *pA1 = ep.Al, *pA2 = ep.A2;
  const f16 *pB0 = ep.Bh, *pB1 = ep.Bl, *pB2 = ep.B2;
  bool stA2 = (NSL == 4), stB1 = (NSL >= 3);
  if constexpr (NSL == 5) {
    if (half2) {
      pA0 = ep.Ch; pA1 = ep.Cl; pA2 = ep.C2; pB0 = ep.Dh;
      stB1 = false; stA2 = true;
    }
  }

  const int srow = w * 16 + (lane >> 2);
  const int scol = (lane & 3) * 8;
  const size_t aoff = zoA + (size_t)(tmr + srow) * 1024 + scol;
  const size_t boff = zoB + (size_t)(tn + srow) * 1024 + scol;
  const f16* gA0 = pA0 + aoff;
  const f16* gA1 = (NSL >= 3) ? pA1 + aoff : pA0 + aoff;
  const f16* gA2 = stA2 ? pA2 + aoff : pA0 + aoff;
  const f16* gB0 = pB0 + boff;
  const f16* gB1 = stB1 ? pB1 + boff : pB0 + boff;
  const f16* gB2 = (NSL == 4) ? pB2 + boff : pB0 + boff;

  const int wr = w >> 1, wc = w & 1;
  const int fr = lane & 15;
  const int kb = (lane >> 4) * 8;
  const int ao = (wr * 64 + fr) * 32 + kb;
  const int bo = (wc * 64 + fr) * 32 + kb;

  auto stage = [&](int kt) {
    GLD(gA0 + kt, SA[0] + w * 512); GLD(gA0 + kt + 65536, SA[0] + 2048 + w * 512);
    GLD(gB0 + kt, SB[0] + w * 512); GLD(gB0 + kt + 65536, SB[0] + 2048 + w * 512);
    if constexpr (NSL >= 3) {
      GLD(gA1 + kt, SA[1] + w * 512); GLD(gA1 + kt + 65536, SA[1] + 2048 + w * 512);
    }
    if constexpr (NSL >= 3) {
      if (stB1) {
        GLD(gB1 + kt, SB[1] + w * 512); GLD(gB1 + kt + 65536, SB[1] + 2048 + w * 512);
      }
    }
    if constexpr (NSL >= 4) {
      if (stA2) {
        GLD(gA2 + kt, SA[NA - 1] + w * 512); GLD(gA2 + kt + 65536, SA[NA - 1] + 2048 + w * 512);
      }
    }
    if constexpr (NSL == 4) {
      GLD(gB2 + kt, SB[2] + w * 512); GLD(gB2 + kt + 65536, SB[2] + 2048 + w * 512);
    }
  };

  f32x4 acc[4][4] = {};
  stage(0);

  for (int kt = 0; kt < 1024; kt += 32) {
    __syncthreads();  // GLDs for this step complete (vmcnt drain)
    f16x8 a0[4], a1[4], a2[4], b0[4], b1[4], b2[4];
#pragma unroll
    for (int i = 0; i < 4; i++) a0[i] = *(const f16x8*)(SA[0] + ao + i * 512);
#pragma unroll
    for (int i = 0; i < 4; i++) b0[i] = *(const f16x8*)(SB[0] + bo + i * 512);
    if constexpr (NSL >= 3) {
#pragma unroll
      for (int i = 0; i < 4; i++) a1[i] = *(const f16x8*)(SA[1] + ao + i * 512);
      if (stB1) {
#pragma unroll
        for (int i = 0; i < 4; i++) b1[i] = *(const f16x8*)(SB[1] + bo + i * 512);
      }
    }
    if constexpr (NSL >= 4) {
      if (stA2) {
#pragma unroll
        for (int i = 0; i < 4; i++) a2[i] = *(const f16x8*)(SA[NA - 1] + ao + i * 512);
      }
    }
    if constexpr (NSL == 4) {
#pragma unroll
      for (int i = 0; i < 4; i++) b2[i] = *(const f16x8*)(SB[2] + bo + i * 512);
    }
    __syncthreads();  // all waves done reading LDS
    if (kt < 992) stage(kt + 32);  // next-step loads fly under MFMA

    auto mm = [&](f16x8 (&fa)[4], f16x8 (&fb)[4]) {
#pragma unroll
      for (int mi = 0; mi < 4; mi++)
#pragma unroll
        for (int ni = 0; ni < 4; ni++)
          acc[mi][ni] = __builtin_amdgcn_mfma_f32_16x16x32_f16(fa[mi], fb[ni], acc[mi][ni], 0, 0, 0);
    };
    mm(a0, b0);
    if constexpr (NSL == 3 || NSL == 4) { mm(a0, b1); mm(a1, b0); }
    if constexpr (NSL == 4) { mm(a2, b2); }
    if constexpr (NSL == 5) {
      if (half2) { mm(a1, b0); mm(a2, b0); }
      else { mm(a0, b1); mm(a1, b0); }
    }
  }

  // C/D layout: col = lane&15, row = (lane>>4)*4 + j
  const int er = wr * 64 + ((lane >> 4) << 2);
  const int ec = wc * 64 + fr;
#pragma unroll
  for (int mi = 0; mi < 4; mi++)
#pragma unroll
    for (int ni = 0; ni < 4; ni++)
#pragma unroll
      for (int j = 0; j < 4; j++) {
        const int r = tmr + er + mi * 16 + j;
        const int c = tn + ec + ni * 16;
        const size_t i = (size_t)r * 1024 + c;
        const float av = acc[mi][ni][j];
        if constexpr (MODE == MZ0) {
          const float z = av * ep.sAi + ep.bias[c];
          wp2(ep.o0h, ep.o0l, i, 0.1f * (z + 0.1f * ep.bias2[c]) * ep.sO);  // 0.1*r1*SIG
          wp2(ep.o1h, ep.o1l, i, 11.f * fmaxf(z, 0.f) * ep.sO);            // r2*SIG
          wp2(ep.o2h, ep.o2l, i, 0.f);                                     // s2 = 0
          ep.of[i] = 0.f;                                                  // s1 = 0
        } else if constexpr (MODE == MVN) {
          const float G = av * ep.sAi;                  // 0.1*r1@Wp + r2@E
          const float r2 = rec2(ep.x0h, ep.x0l, i) * ep.sSi;
          const float v = (r2 + G) * (1.f / 11.f);
          if (ep.dos2) {
            const float s2o = rec2(ep.x2h, ep.x2l, i) * ep.sPi;
            const float vo = rec2(ep.x1h, ep.x1l, i) * ep.sPi;
            const float qo = rec2(ep.x3h, ep.x3l, i) * ep.sPi;
            wp2(ep.o1h, ep.o1l, i, (-r2 - s2o - vo + 10.f * fmaxf(-qo, 0.f)) * ep.sO);  // s2(l)
          }
          wp2(ep.o0h, ep.o0l, i, v * ep.sO);            // v (after reading old v)
        } else if constexpr (MODE == MU || MODE == MUL) {
          const float vW = av * ep.sAi;
          const float r1 = rec2(ep.x0h, ep.x0l, i) * ep.sSi * 10.f;
          const float q = r1 - 0.1f * vW + ep.rf0[i];
          if constexpr (MODE == MU)
            wp2(ep.o0h, ep.o0l, i, q * ep.sO);          // q in-place over r1
          else
            wp2(ep.o0h, ep.o0l, i, -q);                 // logits-u3 (scale 1)
        } else if constexpr (MODE == MQP) {
          if (!half2) {
            const float qW = av * ep.sAi;
            const float v = rec2(ep.x1h, ep.x1l, i) * ep.sSi;
            const float s2 = rec2(ep.x2h, ep.x2l, i) * ep.sSi;
            const float qq = rec2(ep.x0h, ep.x0l, i) * ep.sSi;
            wp2(ep.o0h, ep.o0l, i,
                (10.f * v + 9.f * s2 + 10.f * fmaxf(-qq, 0.f) - 0.1f * qW) * ep.sO2);  // r2'
          } else {
            const float pW = av * ep.sAi;
            const float s1 = ep.rf0[i];
            const float qq = rec2(ep.x0h, ep.x0l, i) * ep.sSi;
            ep.of[i] = -(qq - s1) - 0.1f * pW;                                          // s1'
            wp2(ep.o1h, ep.o1l, i, 0.1f * (0.1f * ep.bias2[c] - s1 + 0.1f * pW) * ep.sO2);  // 0.1*r1'
          }
        } else if constexpr (MODE == MG) {
          const float gv = av * (1.f / 1024.f);
          ep.of[zoO + i] = gv;
          ep.o0h[zoO + i] = (f16)gv;
        } else if constexpr (MODE == ME) {
          constexpr float C1 = 0.01f / 11.f;
          ep.o0h[zoO + i] = (f16)(32.f * (C1 * C1 * av - C1 * ep.rf0[zoO + i]));
        } else if constexpr (MODE == MWP) {
          const float* Wf = ly == 0 ? ep.w0 : ly == 1 ? ep.w1 : ly == 2 ? ep.w2 : ep.w3;
          const float s = 32.f * (Wf[(size_t)c * 1024 + r] + av * (1.f / 1024.f));  // WpT
          const f16 hi = (f16)s;
          ep.o0h[zoO + i] = hi;
          ep.o0l[zoO + i] = (f16)(s - (float)hi);
        }
      }
}

template <int MC>
__global__ void mcprobe() {}  // Mc diagnostic

// x: pad 784->1024, x16, split {h, raw residual}
__global__ __launch_bounds__(256) void xstage(const float* __restrict__ src,
                                              f16* __restrict__ h, f16* __restrict__ l) {
  const size_t i = (size_t)blockIdx.x * 256 + threadIdx.x;
  const int k = (int)(i & 1023);
  const size_t m = i >> 10;
  const float s = (k < 784) ? 16.f * src[m * 784 + k] : 0.f;
  const f16 hi = (f16)s;
  h[i] = hi;
  l[i] = (f16)(s - (float)hi);
}

// Win: pad 784->1024, x32 split
__global__ __launch_bounds__(256) void winstage(const float* __restrict__ src,
                                                f16* __restrict__ h, f16* __restrict__ l) {
  const size_t i = (size_t)blockIdx.x * 256 + threadIdx.x;
  const int k = (int)(i & 1023);
  const size_t m = i >> 10;
  const float s = (k < 784) ? 32.f * src[m * 784 + k] : 0.f;
  const f16 hi = (f16)s;
  h[i] = hi;
  l[i] = (f16)(s - (float)hi);
}

// 4 layer weights -> x32 split, direct + transposed
__global__ __launch_bounds__(256) void wstage(const float* __restrict__ W0, const float* __restrict__ W1,
                                              const float* __restrict__ W2, const float* __restrict__ W3,
                                              f16* __restrict__ Wh, f16* __restrict__ Wl,
                                              f16* __restrict__ WTh, f16* __restrict__ WTl) {
  __shared__ float t[32][33];
  const int lz = blockIdx.z;
  const float* W = lz == 0 ? W0 : lz == 1 ? W1 : lz == 2 ? W2 : W3;
  const size_t off = (size_t)lz * 1024 * 1024;
  const int c0 = blockIdx.x * 32, r0 = blockIdx.y * 32;
  const int tx = threadIdx.x, ty = threadIdx.y;
#pragma unroll
  for (int i = ty; i < 32; i += 8) {
    const float v = W[(size_t)(r0 + i) * 1024 + c0 + tx];
    t[i][tx] = v;
    const float s = 32.f * v;
    const f16 hi = (f16)s;
    Wh[off + (size_t)(r0 + i) * 1024 + c0 + tx] = hi;
    Wl[off + (size_t)(r0 + i) * 1024 + c0 + tx] = (f16)(s - (float)hi);
  }
  __syncthreads();
#pragma unroll
  for (int i = ty; i < 32; i += 8) {
    const float s = 32.f * t[tx][i];
    const f16 hi = (f16)s;
    WTh[off + (size_t)(c0 + i) * 1024 + r0 + tx] = hi;
    WTl[off + (size_t)(c0 + i) * 1024 + r0 + tx] = (f16)(s - (float)hi);
  }
}

// logits = softmax(rec(L) @ Wout^T + bout); one wave per row
__global__ __launch_bounds__(256) void out_softmax(const f16* __restrict__ Lh, const f16* __restrict__ Ll,
                                                   const float* __restrict__ Wout,
                                                   const float* __restrict__ bo,
                                                   float* __restrict__ out) {
  const int row = blockIdx.x * 4 + (threadIdx.x >> 6);
  const int lane = threadIdx.x & 63;
  const size_t rb = (size_t)row * 1024;
  float p[10];
#pragma unroll
  for (int t = 0; t < 10; t++) p[t] = 0.f;
#pragma unroll
  for (int j = 0; j < 4; j++) {
    const int kbase = (j * 64 + lane) * 4;
    const f16x4 hv = *(const f16x4*)(Lh + rb + kbase);
    const f16x4 lv = *(const f16x4*)(Ll + rb + kbase);
    float uv[4];
#pragma unroll
    for (int e = 0; e < 4; e++) uv[e] = (float)hv[e] + (float)lv[e];
#pragma unroll
    for (int t = 0; t < 10; t++) {
      const float4 wv = *(const float4*)(Wout + t * 1024 + kbase);
      p[t] += uv[0] * wv.x + uv[1] * wv.y + uv[2] * wv.z + uv[3] * wv.w;
    }
  }
#pragma unroll
  for (int off = 32; off; off >>= 1)
#pragma unroll
    for (int t = 0; t < 10; t++) p[t] += __shfl_down(p[t], off);
  if (lane == 0) {
    float lg[10], m = -1e30f, s = 0.f;
#pragma unroll
    for (int t = 0; t < 10; t++) { lg[t] = p[t] + bo[t]; m = fmaxf(m, lg[t]); }
#pragma unroll
    for (int t = 0; t < 10; t++) { lg[t] = expf(lg[t] - m); s += lg[t]; }
    const float inv = 1.f / s;
    float* o = out + (size_t)row * 10;
#pragma unroll
    for (int t = 0; t < 10; t++) o[t] = lg[t] * inv;
  }
}

extern "C" void kernel_launch(void* const* d_in, const int* in_sizes, int n_in,
                              void* d_out, int out_size, void* d_ws, size_t ws_size,
                              hipStream_t stream) {
  const float* x = (const float*)d_in[0];
  const float* Win = (const float*)d_in[1];
  const float* bin = (const float*)d_in[2];
  const float* Wgt[4] = {(const float*)d_in[3], (const float*)d_in[5],
                         (const float*)d_in[7], (const float*)d_in[9]};
  const float* bl[4] = {(const float*)d_in[4], (const float*)d_in[6],
                        (const float*)d_in[8], (const float*)d_in[10]};
  const float* Wout = (const float*)d_in[11];
  const float* bout = (const float*)d_in[12];
  float* out = (float*)d_out;

  char* p = (char*)d_ws;
  auto take = [&](size_t n) {
    void* q = (void*)p;
    p += (n + 255) & ~(size_t)255;
    return q;
  };
  const size_t UM = (size_t)1024 * 1024;

  // weights (~60MB)
  f16* Winh = (f16*)take(UM * 2);
  f16* Winl = (f16*)take(UM * 2);
  f16* Wh = (f16*)take(4 * UM * 2);
  f16* Wl = (f16*)take(4 * UM * 2);
  f16* WTh = (f16*)take(4 * UM * 2);
  f16* WTl = (f16*)take(4 * UM * 2);
  f16* WpTh = (f16*)take(4 * UM * 2);
  f16* WpTl = (f16*)take(4 * UM * 2);
  f16* E32 = (f16*)take(4 * UM * 2);
  const size_t fixedB = (size_t)(p - (char*)d_ws);

  int Mc = 8192;
  auto actB = [&](int m) {
    size_t a = (size_t)m * 1024 * 24;  // 10 f16 planes + 1 f32
    if (m < 4096) a += 24 * UM;        // dedicated G scratch
    return a;
  };
  while (Mc > 1024 && fixedB + actB(Mc) + 65536 > ws_size) Mc >>= 1;
  if (fixedB + actB(Mc) + 65536 > ws_size) return;
  const size_t CF = (size_t)Mc * 1024;

  f16* P0h = (f16*)take(CF * 2); f16* P0l = (f16*)take(CF * 2);
  f16* Qh = (f16*)take(CF * 2);  f16* Ql = (f16*)take(CF * 2);
  f16* R2h = (f16*)take(CF * 2); f16* R2l = (f16*)take(CF * 2);
  f16* P2h = (f16*)take(CF * 2); f16* P2l = (f16*)take(CF * 2);
  f16* S2h = (f16*)take(CF * 2); f16* S2l = (f16*)take(CF * 2);
  float* S1 = (float*)take(CF * 4);
  float* Gf;
  f16* Gh;
  if (Mc >= 4096) {    // alias precompute scratch over act planes (dead then)
    Gf = (float*)P0h;  // 16MB over P0h+P0l
    Gh = (f16*)Qh;     // 8MB over Qh
  } else {
    Gf = (float*)take(4 * UM * 4);
    Gh = (f16*)take(4 * UM * 2);
  }

  switch (Mc) {
    case 8192: mcprobe<8><<<1, 1, 0, stream>>>(); break;
    case 4096: mcprobe<4><<<1, 1, 0, stream>>>(); break;
    case 2048: mcprobe<2><<<1, 1, 0, stream>>>(); break;
    default:   mcprobe<1><<<1, 1, 0, stream>>>(); break;
  }

  // ---- weight precompute (batched over 4 layers via blockIdx.z) ----
  winstage<<<dim3((unsigned)(UM / 256)), 256, 0, stream>>>(Win, Winh, Winl);
  wstage<<<dim3(32, 32, 4), dim3(32, 8), 0, stream>>>(Wgt[0], Wgt[1], Wgt[2], Wgt[3],
                                                      Wh, Wl, WTh, WTl);
  {  // G = W^T W (TRI)
    Ep e{};
    e.Ah = WTh; e.Al = WTl; e.Bh = WTh; e.Bl = WTl;
    e.zA = UM; e.zB = UM; e.zO = UM;
    e.of = Gf; e.o0h = Gh;
    gk<MG, 3><<<dim3(8, 8, 4), 256, 0, stream>>>(e);
  }
  {  // E32 = 32*(c^2 G^2 - c G)
    Ep e{};
    e.Ah = Gh; e.Bh = Gh; e.zA = UM; e.zB = UM; e.zO = UM;
    e.rf0 = Gf; e.o0h = E32;
    gk<ME, 1><<<dim3(8, 8, 4), 256, 0, stream>>>(e);
  }
  {  // WpT = W^T + E @ W^T (x32 split)
    Ep e{};
    e.Ah = E32; e.Bh = Wh; e.zA = UM; e.zB = UM; e.zO = UM;
    e.w0 = Wgt[0]; e.w1 = Wgt[1]; e.w2 = Wgt[2]; e.w3 = Wgt[3];
    e.o0h = WpTh; e.o0l = WpTl;
    gk<MWP, 1><<<dim3(8, 8, 4), 256, 0, stream>>>(e);
  }

  const float SIG[5] = {16.f, 2.f, 0.25f, 0.03125f, 1.f};
  const int nch = 8192 / Mc;
  const dim3 gg(8, (unsigned)(Mc / 128));
  const dim3 gg2(8, (unsigned)(Mc / 64));

  for (int ch = 0; ch < nch; ++ch) {
    const size_t r0 = (size_t)ch * Mc;
    xstage<<<dim3(Mc * 4), 256, 0, stream>>>(x + r0 * 784, Qh, Ql);
    {  // Z0: z = x@Win^T + b_in -> P0 (0.1*r1), R2, S2=0, S1=0
      Ep e{};
      e.Ah = Qh; e.Al = Ql; e.Bh = Winh; e.Bl = Winl;
      e.bias = bin; e.bias2 = bl[0];
      e.o0h = P0h; e.o0l = P0l; e.o1h = R2h; e.o1l = R2l; e.o2h = S2h; e.o2l = S2l;
      e.of = S1; e.sAi = 1.f / 512.f; e.sO = 16.f;
      e.Mh = 1 << 30;
      gk<MZ0, 3><<<gg, 256, 0, stream>>>(e);
    }
    for (int l = 0; l < 4; l++) {
      const size_t lz = (size_t)l * UM;
      const float sl = SIG[l];
      f16 *bCh = (l & 1) ? Qh : P0h, *bCl = (l & 1) ? Ql : P0l;  // r1_l -> q_l
      f16 *bAh = (l & 1) ? P0h : Qh, *bAl = (l & 1) ? P0l : Ql;  // q_{l-1} / r1_{l+1}
      {  // VNEW: v = (r2 + 0.1 r1@Wp + r2@E)/11 -> P2 ; s2(l) -> S2 (l>=1)
        Ep e{};
        e.Ah = bCh; e.Al = bCl; e.Bh = WpTh + lz; e.Bl = WpTl + lz;
        e.A2 = R2h; e.B2 = E32 + lz;
        e.x0h = R2h; e.x0l = R2l;
        e.x1h = P2h; e.x1l = P2l;
        e.x2h = S2h; e.x2l = S2l;
        e.x3h = bAh; e.x3l = bAl;
        e.o0h = P2h; e.o0l = P2l; e.o1h = S2h; e.o1l = S2l;
        e.sAi = 1.f / (32.f * sl); e.sSi = 1.f / sl;
        e.sPi = l ? 1.f / SIG[l - 1] : 0.f; e.sO = sl;
        e.dos2 = l ? 1 : 0; e.Mh = 1 << 30;
        gk<MVN, 4><<<gg, 256, 0, stream>>>(e);
      }
      if (l < 3) {
        {  // U: q = 10*(0.1 r1) - 0.1 v@W^T + s1 -> in-place over r1
          Ep e{};
          e.Ah = P2h; e.Al = P2l; e.Bh = Wh + lz; e.Bl = Wl + lz;
          e.x0h = bCh; e.x0l = bCl; e.rf0 = S1;
          e.o0h = bCh; e.o0l = bCl;
          e.sAi = 1.f / (32.f * sl); e.sSi = 1.f / sl; e.sO = sl;
          e.Mh = 1 << 30;
          gk<MU, 3><<<gg, 256, 0, stream>>>(e);
        }
        {  // QP: q-half q@W -> r2' ; p-half (v+s2h)@W^T -> s1', r1'
          Ep e{};
          e.Ah = bCh; e.Al = bCl; e.Bh = WTh + lz; e.Bl = WTl + lz;
          e.Ch = P2h; e.Cl = P2l; e.C2 = S2h; e.Dh = Wh + lz;
          e.x0h = bCh; e.x0l = bCl;
          e.x1h = P2h; e.x1l = P2l;
          e.x2h = S2h; e.x2l = S2l;
          e.rf0 = S1; e.of = S1;
          e.o0h = R2h; e.o0l = R2l;    // r2'
          e.o1h = bAh; e.o1l = bAl;    // 0.1*r1'
          e.bias2 = bl[l + 1];
          e.sAi = 1.f / (32.f * sl); e.sSi = 1.f / sl; e.sO2 = SIG[l + 1];
          e.Mh = Mc;
          gk<MQP, 5><<<gg2, 256, 0, stream>>>(e);
        }
      } else {  // UL: logits = -(10*(0.1 r1) - 0.1 v@W^T + s1) -> R2 pair (scale 1)
        Ep e{};
        e.Ah = P2h; e.Al = P2l; e.Bh = Wh + lz; e.Bl = Wl + lz;
        e.x0h = bCh; e.x0l = bCl; e.rf0 = S1;
        e.o0h = R2h; e.o0l = R2l;
        e.sAi = 1.f / (32.f * sl); e.sSi = 1.f / sl; e.sO = 1.f;
        e.Mh = 1 << 30;
        gk<MUL, 3><<<gg, 256, 0, stream>>>(e);
      }
    }
    out_softmax<<<dim3(Mc / 4), 256, 0, stream>>>(R2h, R2l, Wout, bout, out + r0 * 10);
  }
}